// Round 8
// baseline (479.592 us; speedup 1.0000x reference)
//
#include <hip/hip_runtime.h>
#include <hip/hip_bf16.h>

typedef __attribute__((ext_vector_type(8))) short   s16x8;
typedef __attribute__((ext_vector_type(4))) short   s16x4;
typedef __attribute__((ext_vector_type(8))) __bf16  bf16x8;
typedef __attribute__((ext_vector_type(4))) float   f32x4;

__device__ __forceinline__ short f2bf(float f) {
  unsigned u = __builtin_bit_cast(unsigned, f);
  u += 0x7fffu + ((u >> 16) & 1u);          // round-to-nearest-even
  return (short)(u >> 16);
}

// pack two f32 -> two bf16 in a u32 (round-half-up; bit-exact, no ISA ambiguity)
__device__ __forceinline__ unsigned pack2bf(float a, float b) {
  unsigned ua = __builtin_bit_cast(unsigned, a) + 0x8000u;
  unsigned ub = __builtin_bit_cast(unsigned, b) + 0x8000u;
  return (ua >> 16) | (ub & 0xffff0000u);
}

__device__ __forceinline__ f32x4 mfma16(s16x8 a, s16x8 b, f32x4 c) {
  return __builtin_amdgcn_mfma_f32_16x16x32_bf16(
      __builtin_bit_cast(bf16x8, a), __builtin_bit_cast(bf16x8, b), c, 0, 0, 0);
}

__device__ __forceinline__ void glds16(const short* g, short* l) {
  __builtin_amdgcn_global_load_lds(
      (__attribute__((address_space(1))) const void*)g,
      (__attribute__((address_space(3))) void*)l, 16, 0, 0);
}

// ---------------- merged transpose + cast of the 3 weights ----------------
// W_reduce 768x384 (288 blk), W_qkv 384x1152 (432 blk), W_proj 384x768 (288 blk)
__global__ __launch_bounds__(256) void transpose_cast_all(
    const float* __restrict__ s0, short* __restrict__ d0,
    const float* __restrict__ s1, short* __restrict__ d1,
    const float* __restrict__ s2, short* __restrict__ d2) {
  __shared__ float t[32 * 33];
  int id = blockIdx.x;
  const float* src; short* dst; int R, C, bx, by;
  if (id < 288)      { src = s0; dst = d0; R = 768; C = 384;  bx = id % 12;           by = id / 12; }
  else if (id < 720) { int l = id - 288; src = s1; dst = d1; R = 384; C = 1152; bx = l % 36; by = l / 36; }
  else               { int l = id - 720; src = s2; dst = d2; R = 384; C = 768;  bx = l % 24; by = l / 24; }
  int tid = threadIdx.x;
  int c0 = bx * 32, r0 = by * 32;
  for (int rep = 0; rep < 4; ++rep) {
    int idx = rep * 256 + tid;
    int rr = idx >> 5, cc = idx & 31;
    t[rr * 33 + cc] = src[(size_t)(r0 + rr) * C + c0 + cc];
  }
  __syncthreads();
  for (int rep = 0; rep < 4; ++rep) {
    int idx = rep * 256 + tid;
    int cc = idx >> 5, rr = idx & 31;
    dst[(size_t)(c0 + cc) * R + r0 + rr] = f2bf(t[rr * 33 + cc]);
  }
}

// ---------------- m97-style bf16 GEMM: A[M][K] x Bt[N][K] + bias -> out ----------------
// MODE 0: bf16 row-major out. MODE 1: f32 row-major out.
// MODE 2: qkv scatter -> q_p/k_p[bhs][1024][32] bf16, vtok[16384][384] bf16.
// AF32: A is f32 in global; reg-stage (issue early, convert+ds_write after MFMA).
template <int MODE, bool AF32>
__global__ __launch_bounds__(256, 2) void gemm_bf16(
    const short* __restrict__ A, const float* __restrict__ Af,
    const short* __restrict__ Bt,
    const float* __restrict__ bias, void* __restrict__ out,
    short* __restrict__ q_p, short* __restrict__ k_p, short* __restrict__ vtok,
    int M, int N, int K) {
  __shared__ short lds[2][2][128 * 64];
  int tid = threadIdx.x;
  int lane = tid & 63, wid = tid >> 6;
  int l15 = lane & 15, g = lane >> 4;
  int nbn = N >> 7;
  int nwg = gridDim.x;
  int bid = blockIdx.x;
  int chunk = nwg >> 3;                       // all grids are %8 == 0
  int swz_bid = (bid & 7) * chunk + (bid >> 3);
  int bm = swz_bid / nbn, bn = swz_bid % nbn;
  int wr = wid >> 1, wc = wid & 1;

  const short* Ab = AF32 ? nullptr : (A + (size_t)(bm * 128) * K);
  const float* Afb = AF32 ? (Af + (size_t)(bm * 128) * K) : nullptr;
  const short* Bb = Bt + (size_t)(bn * 128) * K;

  f32x4 acc[4][4];
#pragma unroll
  for (int i = 0; i < 4; ++i)
#pragma unroll
    for (int j = 0; j < 4; ++j) acc[i][j] = (f32x4){0.f, 0.f, 0.f, 0.f};

  f32x4 areg[4][2];                           // AF32: 8 floats per c-slot
  int nk = K >> 6;

  auto stageB = [&](int bufi, int kt) {
    const short* gb = Bb + kt * 64;
#pragma unroll
    for (int it = 0; it < 4; ++it) {
      int c = it * 256 + tid;
      int row = c >> 3, pc = c & 7;
      int lc = pc ^ (row & 7);                // pre-swizzled source (rule #21)
      glds16(gb + (size_t)row * K + lc * 8, &lds[bufi][1][(it * 256 + wid * 64) * 8]);
    }
  };
  auto stageA_lds = [&](int bufi, int kt) {
    const short* ga = Ab + kt * 64;
#pragma unroll
    for (int it = 0; it < 4; ++it) {
      int c = it * 256 + tid;
      int row = c >> 3, pc = c & 7;
      int lc = pc ^ (row & 7);
      glds16(ga + (size_t)row * K + lc * 8, &lds[bufi][0][(it * 256 + wid * 64) * 8]);
    }
  };
  auto stageA_issue = [&](int kt) {           // f32 global -> regs (no wait yet)
#pragma unroll
    for (int it = 0; it < 4; ++it) {
      int c = it * 256 + tid;
      int row = c >> 3, pc = c & 7;
      int lc = pc ^ (row & 7);
      const float* src = Afb + (size_t)row * K + kt * 64 + lc * 8;
      areg[it][0] = *(const f32x4*)(src);
      areg[it][1] = *(const f32x4*)(src + 4);
    }
  };
  auto stageA_write = [&](int bufi) {         // regs -> bf16 -> LDS (same image)
#pragma unroll
    for (int it = 0; it < 4; ++it) {
      int c = it * 256 + tid;
      s16x8 o;
#pragma unroll
      for (int q = 0; q < 4; ++q) {
        o[q]     = f2bf(areg[it][0][q]);
        o[q + 4] = f2bf(areg[it][1][q]);
      }
      *(s16x8*)(&lds[0][0][0] + ((size_t)bufi * 2 * 128 * 64) + (size_t)c * 8) = o;
    }
  };

  if (AF32) { stageA_issue(0); stageB(0, 0); stageA_write(0); }
  else      { stageA_lds(0, 0); stageB(0, 0); }
  __syncthreads();
  int buf = 0;
  for (int kt = 0; kt < nk; ++kt) {
    bool more = (kt + 1 < nk);
    if (more) {
      if (AF32) stageA_issue(kt + 1); else stageA_lds(buf ^ 1, kt + 1);
      stageB(buf ^ 1, kt + 1);
    }
    const short* la = &lds[buf][0][0];
    const short* lb = &lds[buf][1][0];
    s16x8 af[4][2], bfv[4][2];
#pragma unroll
    for (int i = 0; i < 4; ++i)
#pragma unroll
      for (int kk = 0; kk < 2; ++kk) {
        int row = wr * 64 + i * 16 + l15;
        int ch = (kk * 4 + g) ^ (l15 & 7);
        af[i][kk] = *(const s16x8*)(la + row * 64 + ch * 8);
      }
#pragma unroll
    for (int j = 0; j < 4; ++j)
#pragma unroll
      for (int kk = 0; kk < 2; ++kk) {
        int row = wc * 64 + j * 16 + l15;
        int ch = (kk * 4 + g) ^ (l15 & 7);
        bfv[j][kk] = *(const s16x8*)(lb + row * 64 + ch * 8);
      }
#pragma unroll
    for (int kk = 0; kk < 2; ++kk)
#pragma unroll
      for (int i = 0; i < 4; ++i)
#pragma unroll
        for (int j = 0; j < 4; ++j)
          acc[i][j] = mfma16(af[i][kk], bfv[j][kk], acc[i][j]);
    if (AF32 && more) stageA_write(buf ^ 1);  // HBM latency hidden under MFMA
    __syncthreads();
    buf ^= 1;
  }

#pragma unroll
  for (int j = 0; j < 4; ++j) {
    int col = bn * 128 + wc * 64 + j * 16 + l15;
    float bv = bias[col];
    int which = 0, rem = 0, h = 0, d = 0;
    if (MODE == 2) {
      which = col / 384;
      rem = col - which * 384;
      h = rem >> 5; d = rem & 31;
    }
#pragma unroll
    for (int i = 0; i < 4; ++i) {
      int row0 = bm * 128 + wr * 64 + i * 16 + g * 4;
#pragma unroll
      for (int r = 0; r < 4; ++r) {
        int row = row0 + r;
        float v = acc[i][j][r] + bv;
        if (MODE == 1) {
          ((float*)out)[(size_t)row * N + col] = v;
        } else if (MODE == 0) {
          ((short*)out)[(size_t)row * N + col] = f2bf(v);
        } else {
          short bf = f2bf(v);
          if (which == 2) {
            vtok[(size_t)row * 384 + rem] = bf;
          } else {
            int b = row >> 12, s = (row >> 10) & 3, key = row & 1023;
            size_t dst = ((size_t)((b * 12 + h) * 4 + s) << 15) + key * 32 + d;
            if (which) k_p[dst] = bf; else q_p[dst] = bf;
          }
        }
      }
    }
  }
}

// ---------------- V transpose: vtok [16384][384] -> vt[bhs][32][1024] ----------------
__global__ __launch_bounds__(256) void v_transpose(
    const short* __restrict__ vtok, short* __restrict__ vt) {
  __shared__ short t[256 * 33];
  int tid = threadIdx.x;
  int bid = blockIdx.x;                        // 192*4
  int kc = bid & 3, bhs = bid >> 2;
  int s = bhs & 3, h = (bhs >> 2) % 12, b = bhs / 48;
  int key = kc * 256 + tid;
  int tok = b * 4096 + s * 1024 + key;
  const short* src = vtok + (size_t)tok * 384 + h * 32;
#pragma unroll
  for (int c = 0; c < 4; ++c) {
    s16x8 v = *(const s16x8*)(src + c * 8);
#pragma unroll
    for (int j = 0; j < 8; ++j) t[tid * 33 + c * 8 + j] = v[j];
  }
  __syncthreads();
  int d = tid >> 3, kb = tid & 7;
  short* dst = vt + ((size_t)((b * 12 + h) * 4 + s)) * 32768 + (size_t)d * 1024 + kc * 256 + kb * 32;
#pragma unroll
  for (int cc = 0; cc < 4; ++cc) {
    s16x8 o;
#pragma unroll
    for (int j = 0; j < 8; ++j) o[j] = t[(kb * 32 + cc * 8 + j) * 33 + d];
    *(s16x8*)(dst + cc * 8) = o;
  }
}

// ---------------- flash attention: swapped QK^T, i-split for occupancy ----------------
// grid = 8 q-tiles * 192 bhs, bid = qt*192 + bhs (XCD locality on bhs).
// 4 waves * 32 q-rows; KVBLK=128; hd=32. Per kv-tile, the two 16-row halves (i=0,1)
// run QK->softmax->PV sequentially so the per-wave P buffer is 16x272B = 4.3KB
// (block 17.4KB -> ~9 blocks/CU by LDS; grid provides 6/CU). kf/vf re-loads for
// the second half hit L1 (same 8KB tile, ~200 instr apart).
// S^T = mfma(K, Q): lane holds q = l15, keys kn*16 + g*4 + {0..3}.
// Fixed-shift softmax (validated r5); manual bf16 pack (validated r6).
__global__ __launch_bounds__(256, 6) void attn_kernel(
    const short* __restrict__ qp, const short* __restrict__ kp,
    const short* __restrict__ vt, short* __restrict__ ob) {
  __shared__ short plds[4][16 * 136];          // per-wave P[16][272B]
  int tid = threadIdx.x;
  int lane = tid & 63, w = tid >> 6;
  int l15 = lane & 15, g = lane >> 4;
  int bid = blockIdx.x;
  int bhs = bid % 192, qt = bid / 192;
  int s = bhs & 3, h = (bhs >> 2) % 12, b = bhs / 48;
  const float ce = 0.17677669529663687f * 1.4426950408889634f;  // hd^-0.5 * log2(e)
  const float csh = 12.0f * 1.4426950408889634f;                // fixed shift

  const short* qb = qp + ((size_t)bhs << 15) + (qt * 128 + w * 32) * 32;
  const short* kb = kp + ((size_t)bhs << 15);
  const short* vb = vt + ((size_t)bhs << 15);

  s16x8 qf[2];
#pragma unroll
  for (int i = 0; i < 2; ++i)
    qf[i] = *(const s16x8*)(qb + (i * 16 + l15) * 32 + g * 8);

  f32x4 oacc[2][2];
#pragma unroll
  for (int i = 0; i < 2; ++i)
#pragma unroll
    for (int n = 0; n < 2; ++n) oacc[i][n] = (f32x4){0.f, 0.f, 0.f, 0.f};
  float lsum[2] = {0.f, 0.f};

  char* pw = (char*)&plds[w][0];
  int swz = (l15 >> 3) << 4;                   // 1-bit XOR (row-pure, bijective)

  for (int t = 0; t < 8; ++t) {
#pragma unroll
    for (int i = 0; i < 2; ++i) {              // static unroll (rule #20)
      f32x4 sa[8];
      __builtin_amdgcn_s_setprio(1);
#pragma unroll
      for (int kn = 0; kn < 8; ++kn) {
        s16x8 kf = *(const s16x8*)(kb + (size_t)(t * 128 + kn * 16 + l15) * 32 + g * 8);
        sa[kn] = mfma16(kf, qf[i], (f32x4){0.f, 0.f, 0.f, 0.f});
      }
      __builtin_amdgcn_s_setprio(0);
      // fixed-shift numerators; lane owns query l15 (this half), keys kn*16+g*4+{0..3}
      float ps = 0.f;
#pragma unroll
      for (int kn = 0; kn < 8; ++kn) {
        float p0 = __builtin_amdgcn_exp2f(sa[kn][0] * ce - csh);
        float p1 = __builtin_amdgcn_exp2f(sa[kn][1] * ce - csh);
        float p2 = __builtin_amdgcn_exp2f(sa[kn][2] * ce - csh);
        float p3 = __builtin_amdgcn_exp2f(sa[kn][3] * ce - csh);
        ps += (p0 + p1) + (p2 + p3);
        uint2 u;
        u.x = pack2bf(p0, p1);
        u.y = pack2bf(p2, p3);
        *(s16x4*)(pw + l15 * 272 + ((kn * 32 + g * 8) ^ swz)) =
            __builtin_bit_cast(s16x4, u);
      }
      lsum[i] += ps;                           // per-lane partial; reduced at end
      // pin P-store phase before PV-read phase (same-wave LDS, no barrier needed)
      __builtin_amdgcn_sched_barrier(0);
      __builtin_amdgcn_s_setprio(1);
#pragma unroll
      for (int kk = 0; kk < 4; ++kk) {
        s16x8 pa = *(const s16x8*)(pw + l15 * 272 + ((kk * 64 + g * 16) ^ swz));
#pragma unroll
        for (int n = 0; n < 2; ++n) {
          s16x8 vf = *(const s16x8*)(vb + (size_t)(n * 16 + l15) * 1024 + t * 128 + kk * 32 + g * 8);
          oacc[i][n] = mfma16(vf, pa, oacc[i][n]);
        }
      }
      __builtin_amdgcn_s_setprio(0);
      // next half's P-stores must not move above this half's P-loads
      __builtin_amdgcn_sched_barrier(0);
    }
  }
  // final denominator: sum across the 4 g-groups (keys partition over g)
#pragma unroll
  for (int i = 0; i < 2; ++i) {
    float v = lsum[i];
    v += __shfl_xor(v, 16);
    v += __shfl_xor(v, 32);
    lsum[i] = v;
  }
  int tokq0 = b * 4096 + s * 1024 + qt * 128 + w * 32;
#pragma unroll
  for (int i = 0; i < 2; ++i) {
    float inv = 1.0f / lsum[i];
    int tok = tokq0 + i * 16 + l15;
#pragma unroll
    for (int n = 0; n < 2; ++n) {
      uint2 u;
      u.x = pack2bf(oacc[i][n][0] * inv, oacc[i][n][1] * inv);
      u.y = pack2bf(oacc[i][n][2] * inv, oacc[i][n][3] * inv);
      *(s16x4*)(ob + (size_t)tok * 384 + h * 32 + n * 16 + g * 4) =
          __builtin_bit_cast(s16x4, u);
    }
  }
}

// ---------------- launch ----------------
extern "C" void kernel_launch(void* const* d_in, const int* in_sizes, int n_in,
                              void* d_out, int out_size, void* d_ws, size_t ws_size,
                              hipStream_t stream) {
  const float* x        = (const float*)d_in[0];   // [4,4096,768]
  const float* W_reduce = (const float*)d_in[1];   // [768,384]
  const float* b_reduce = (const float*)d_in[2];   // [384]
  const float* W_qkv    = (const float*)d_in[3];   // [384,1152]
  const float* b_qkv    = (const float*)d_in[4];   // [1152]
  const float* W_proj   = (const float*)d_in[5];   // [384,768]
  const float* b_proj   = (const float*)d_in[6];   // [768]
  float* out = (float*)d_out;                      // [16384,768]

  char* ws = (char*)d_ws;
  short* wr_t    = (short*)(ws + 0);               // [384][768]    589824 B
  short* wqkv_t  = (short*)(ws + 589824);          // [1152][384]   884736 B
  short* wproj_t = (short*)(ws + 1474560);         // [768][384]    589824 B
  short* xr_b    = (short*)(ws + 2064384);         // [16384][384]  12582912 B
  short* o_b     = xr_b;                           // reuse after qkv GEMM
  short* q_p     = (short*)(ws + 14647296);        // [192][1024][32] 12582912 B
  short* k_p     = (short*)(ws + 27230208);        // 12582912 B
  short* vtok    = (short*)(ws + 39813120);        // [16384][384]  12582912 B
  short* vt      = (short*)(ws + 52396032);        // [192][32][1024] 12582912 B; ends 64978944

  // all three weight transposes in one dispatch
  transpose_cast_all<<<1008, 256, 0, stream>>>(W_reduce, wr_t, W_qkv, wqkv_t, W_proj, wproj_t);

  // xr = x @ W_reduce + b_reduce  (f32 A fused-cast, bf16 out)
  gemm_bf16<0, true><<<384, 256, 0, stream>>>(nullptr, x, wr_t, b_reduce, xr_b,
                                              nullptr, nullptr, nullptr, 16384, 384, 768);
  // qkv = xr @ W_qkv + b_qkv  -> scatter to q_p / k_p / vtok
  gemm_bf16<2, false><<<1152, 256, 0, stream>>>(xr_b, nullptr, wqkv_t, b_qkv, nullptr,
                                                q_p, k_p, vtok, 16384, 1152, 384);
  // v transpose for PV fragments
  v_transpose<<<768, 256, 0, stream>>>(vtok, vt);
  // attention -> o_b
  attn_kernel<<<1536, 256, 0, stream>>>(q_p, k_p, vt, o_b);
  // out = o @ W_proj + b_proj (f32 out)
  gemm_bf16<1, false><<<768, 256, 0, stream>>>(o_b, nullptr, wproj_t, b_proj, (void*)out,
                                               nullptr, nullptr, nullptr, 16384, 768, 384);
}

// Round 9
// 308.565 us; speedup vs baseline: 1.5543x; 1.5543x over previous
//
#include <hip/hip_runtime.h>
#include <hip/hip_bf16.h>

typedef __attribute__((ext_vector_type(8))) short   s16x8;
typedef __attribute__((ext_vector_type(4))) short   s16x4;
typedef __attribute__((ext_vector_type(8))) __bf16  bf16x8;
typedef __attribute__((ext_vector_type(4))) float   f32x4;

__device__ __forceinline__ short f2bf(float f) {
  unsigned u = __builtin_bit_cast(unsigned, f);
  u += 0x7fffu + ((u >> 16) & 1u);          // round-to-nearest-even
  return (short)(u >> 16);
}

// pack two f32 -> two bf16 in a u32 (round-half-up; bit-exact, no ISA ambiguity)
__device__ __forceinline__ unsigned pack2bf(float a, float b) {
  unsigned ua = __builtin_bit_cast(unsigned, a) + 0x8000u;
  unsigned ub = __builtin_bit_cast(unsigned, b) + 0x8000u;
  return (ua >> 16) | (ub & 0xffff0000u);
}

__device__ __forceinline__ f32x4 mfma16(s16x8 a, s16x8 b, f32x4 c) {
  return __builtin_amdgcn_mfma_f32_16x16x32_bf16(
      __builtin_bit_cast(bf16x8, a), __builtin_bit_cast(bf16x8, b), c, 0, 0, 0);
}

__device__ __forceinline__ void glds16(const short* g, short* l) {
  __builtin_amdgcn_global_load_lds(
      (__attribute__((address_space(1))) const void*)g,
      (__attribute__((address_space(3))) void*)l, 16, 0, 0);
}

// ---------------- merged transpose + cast of the 3 weights ----------------
// W_reduce 768x384 (288 blk), W_qkv 384x1152 (432 blk), W_proj 384x768 (288 blk)
__global__ __launch_bounds__(256) void transpose_cast_all(
    const float* __restrict__ s0, short* __restrict__ d0,
    const float* __restrict__ s1, short* __restrict__ d1,
    const float* __restrict__ s2, short* __restrict__ d2) {
  __shared__ float t[32 * 33];
  int id = blockIdx.x;
  const float* src; short* dst; int R, C, bx, by;
  if (id < 288)      { src = s0; dst = d0; R = 768; C = 384;  bx = id % 12;           by = id / 12; }
  else if (id < 720) { int l = id - 288; src = s1; dst = d1; R = 384; C = 1152; bx = l % 36; by = l / 36; }
  else               { int l = id - 720; src = s2; dst = d2; R = 384; C = 768;  bx = l % 24; by = l / 24; }
  int tid = threadIdx.x;
  int c0 = bx * 32, r0 = by * 32;
  for (int rep = 0; rep < 4; ++rep) {
    int idx = rep * 256 + tid;
    int rr = idx >> 5, cc = idx & 31;
    t[rr * 33 + cc] = src[(size_t)(r0 + rr) * C + c0 + cc];
  }
  __syncthreads();
  for (int rep = 0; rep < 4; ++rep) {
    int idx = rep * 256 + tid;
    int cc = idx >> 5, rr = idx & 31;
    dst[(size_t)(c0 + cc) * R + r0 + rr] = f2bf(t[rr * 33 + cc]);
  }
}

// ---------------- m97-style bf16 GEMM: A[M][K] x Bt[N][K] + bias -> out ----------------
// MODE 0: bf16 row-major out. MODE 1: f32 row-major out.
// MODE 2: qkv scatter -> q_p/k_p[bhs][1024][32] bf16, vtok[16384][384] bf16.
// AF32: A is f32 in global; reg-stage (issue early, convert+ds_write after MFMA).
template <int MODE, bool AF32>
__global__ __launch_bounds__(256, 2) void gemm_bf16(
    const short* __restrict__ A, const float* __restrict__ Af,
    const short* __restrict__ Bt,
    const float* __restrict__ bias, void* __restrict__ out,
    short* __restrict__ q_p, short* __restrict__ k_p, short* __restrict__ vtok,
    int M, int N, int K) {
  __shared__ short lds[2][2][128 * 64];
  int tid = threadIdx.x;
  int lane = tid & 63, wid = tid >> 6;
  int l15 = lane & 15, g = lane >> 4;
  int nbn = N >> 7;
  int nwg = gridDim.x;
  int bid = blockIdx.x;
  int chunk = nwg >> 3;                       // all grids are %8 == 0
  int swz_bid = (bid & 7) * chunk + (bid >> 3);
  int bm = swz_bid / nbn, bn = swz_bid % nbn;
  int wr = wid >> 1, wc = wid & 1;

  const short* Ab = AF32 ? nullptr : (A + (size_t)(bm * 128) * K);
  const float* Afb = AF32 ? (Af + (size_t)(bm * 128) * K) : nullptr;
  const short* Bb = Bt + (size_t)(bn * 128) * K;

  f32x4 acc[4][4];
#pragma unroll
  for (int i = 0; i < 4; ++i)
#pragma unroll
    for (int j = 0; j < 4; ++j) acc[i][j] = (f32x4){0.f, 0.f, 0.f, 0.f};

  f32x4 areg[4][2];                           // AF32: 8 floats per c-slot
  int nk = K >> 6;

  auto stageB = [&](int bufi, int kt) {
    const short* gb = Bb + kt * 64;
#pragma unroll
    for (int it = 0; it < 4; ++it) {
      int c = it * 256 + tid;
      int row = c >> 3, pc = c & 7;
      int lc = pc ^ (row & 7);                // pre-swizzled source (rule #21)
      glds16(gb + (size_t)row * K + lc * 8, &lds[bufi][1][(it * 256 + wid * 64) * 8]);
    }
  };
  auto stageA_lds = [&](int bufi, int kt) {
    const short* ga = Ab + kt * 64;
#pragma unroll
    for (int it = 0; it < 4; ++it) {
      int c = it * 256 + tid;
      int row = c >> 3, pc = c & 7;
      int lc = pc ^ (row & 7);
      glds16(ga + (size_t)row * K + lc * 8, &lds[bufi][0][(it * 256 + wid * 64) * 8]);
    }
  };
  auto stageA_issue = [&](int kt) {           // f32 global -> regs (no wait yet)
#pragma unroll
    for (int it = 0; it < 4; ++it) {
      int c = it * 256 + tid;
      int row = c >> 3, pc = c & 7;
      int lc = pc ^ (row & 7);
      const float* src = Afb + (size_t)row * K + kt * 64 + lc * 8;
      areg[it][0] = *(const f32x4*)(src);
      areg[it][1] = *(const f32x4*)(src + 4);
    }
  };
  auto stageA_write = [&](int bufi) {         // regs -> bf16 -> LDS (same image)
#pragma unroll
    for (int it = 0; it < 4; ++it) {
      int c = it * 256 + tid;
      s16x8 o;
#pragma unroll
      for (int q = 0; q < 4; ++q) {
        o[q]     = f2bf(areg[it][0][q]);
        o[q + 4] = f2bf(areg[it][1][q]);
      }
      *(s16x8*)(&lds[0][0][0] + ((size_t)bufi * 2 * 128 * 64) + (size_t)c * 8) = o;
    }
  };

  if (AF32) { stageA_issue(0); stageB(0, 0); stageA_write(0); }
  else      { stageA_lds(0, 0); stageB(0, 0); }
  __syncthreads();
  int buf = 0;
  for (int kt = 0; kt < nk; ++kt) {
    bool more = (kt + 1 < nk);
    if (more) {
      if (AF32) stageA_issue(kt + 1); else stageA_lds(buf ^ 1, kt + 1);
      stageB(buf ^ 1, kt + 1);
    }
    const short* la = &lds[buf][0][0];
    const short* lb = &lds[buf][1][0];
    s16x8 af[4][2], bfv[4][2];
#pragma unroll
    for (int i = 0; i < 4; ++i)
#pragma unroll
      for (int kk = 0; kk < 2; ++kk) {
        int row = wr * 64 + i * 16 + l15;
        int ch = (kk * 4 + g) ^ (l15 & 7);
        af[i][kk] = *(const s16x8*)(la + row * 64 + ch * 8);
      }
#pragma unroll
    for (int j = 0; j < 4; ++j)
#pragma unroll
      for (int kk = 0; kk < 2; ++kk) {
        int row = wc * 64 + j * 16 + l15;
        int ch = (kk * 4 + g) ^ (l15 & 7);
        bfv[j][kk] = *(const s16x8*)(lb + row * 64 + ch * 8);
      }
#pragma unroll
    for (int kk = 0; kk < 2; ++kk)
#pragma unroll
      for (int i = 0; i < 4; ++i)
#pragma unroll
        for (int j = 0; j < 4; ++j)
          acc[i][j] = mfma16(af[i][kk], bfv[j][kk], acc[i][j]);
    if (AF32 && more) stageA_write(buf ^ 1);  // HBM latency hidden under MFMA
    __syncthreads();
    buf ^= 1;
  }

#pragma unroll
  for (int j = 0; j < 4; ++j) {
    int col = bn * 128 + wc * 64 + j * 16 + l15;
    float bv = bias[col];
    int which = 0, rem = 0, h = 0, d = 0;
    if (MODE == 2) {
      which = col / 384;
      rem = col - which * 384;
      h = rem >> 5; d = rem & 31;
    }
#pragma unroll
    for (int i = 0; i < 4; ++i) {
      int row0 = bm * 128 + wr * 64 + i * 16 + g * 4;
#pragma unroll
      for (int r = 0; r < 4; ++r) {
        int row = row0 + r;
        float v = acc[i][j][r] + bv;
        if (MODE == 1) {
          ((float*)out)[(size_t)row * N + col] = v;
        } else if (MODE == 0) {
          ((short*)out)[(size_t)row * N + col] = f2bf(v);
        } else {
          short bf = f2bf(v);
          if (which == 2) {
            vtok[(size_t)row * 384 + rem] = bf;
          } else {
            int b = row >> 12, s = (row >> 10) & 3, key = row & 1023;
            size_t dst = ((size_t)((b * 12 + h) * 4 + s) << 15) + key * 32 + d;
            if (which) k_p[dst] = bf; else q_p[dst] = bf;
          }
        }
      }
    }
  }
}

// ---------------- V transpose: vtok [16384][384] -> vt[bhs][32][1024] ----------------
__global__ __launch_bounds__(256) void v_transpose(
    const short* __restrict__ vtok, short* __restrict__ vt) {
  __shared__ short t[256 * 33];
  int tid = threadIdx.x;
  int bid = blockIdx.x;                        // 192*4
  int kc = bid & 3, bhs = bid >> 2;
  int s = bhs & 3, h = (bhs >> 2) % 12, b = bhs / 48;
  int key = kc * 256 + tid;
  int tok = b * 4096 + s * 1024 + key;
  const short* src = vtok + (size_t)tok * 384 + h * 32;
#pragma unroll
  for (int c = 0; c < 4; ++c) {
    s16x8 v = *(const s16x8*)(src + c * 8);
#pragma unroll
    for (int j = 0; j < 8; ++j) t[tid * 33 + c * 8 + j] = v[j];
  }
  __syncthreads();
  int d = tid >> 3, kb = tid & 7;
  short* dst = vt + ((size_t)((b * 12 + h) * 4 + s)) * 32768 + (size_t)d * 1024 + kc * 256 + kb * 32;
#pragma unroll
  for (int cc = 0; cc < 4; ++cc) {
    s16x8 o;
#pragma unroll
    for (int j = 0; j < 8; ++j) o[j] = t[(kb * 32 + cc * 8 + j) * 33 + d];
    *(s16x8*)(dst + cc * 8) = o;
  }
}

// ---------------- flash attention: swapped QK^T, i-split for occupancy ----------------
// grid = 8 q-tiles * 192 bhs, bid = qt*192 + bhs (XCD locality on bhs).
// 4 waves * 32 q-rows; KVBLK=128; hd=32. Per kv-tile, the two 16-row halves (i=0,1)
// run QK->softmax->PV sequentially so the per-wave P buffer is 16x272B = 4.3KB
// (block 17.4KB). launch_bounds min-waves=4 (VGPR cap 128): natural alloc ~60 VGPR,
// NO spill — bounds(256,6) in r8 forced VGPR=40 and 1.9GB of scratch traffic.
// S^T = mfma(K, Q): lane holds q = l15, keys kn*16 + g*4 + {0..3}.
// Fixed-shift softmax (validated r5); manual bf16 pack (validated r6).
__global__ __launch_bounds__(256, 4) void attn_kernel(
    const short* __restrict__ qp, const short* __restrict__ kp,
    const short* __restrict__ vt, short* __restrict__ ob) {
  __shared__ short plds[4][16 * 136];          // per-wave P[16][272B]
  int tid = threadIdx.x;
  int lane = tid & 63, w = tid >> 6;
  int l15 = lane & 15, g = lane >> 4;
  int bid = blockIdx.x;
  int bhs = bid % 192, qt = bid / 192;
  int s = bhs & 3, h = (bhs >> 2) % 12, b = bhs / 48;
  const float ce = 0.17677669529663687f * 1.4426950408889634f;  // hd^-0.5 * log2(e)
  const float csh = 12.0f * 1.4426950408889634f;                // fixed shift

  const short* qb = qp + ((size_t)bhs << 15) + (qt * 128 + w * 32) * 32;
  const short* kb = kp + ((size_t)bhs << 15);
  const short* vb = vt + ((size_t)bhs << 15);

  s16x8 qf[2];
#pragma unroll
  for (int i = 0; i < 2; ++i)
    qf[i] = *(const s16x8*)(qb + (i * 16 + l15) * 32 + g * 8);

  f32x4 oacc[2][2];
#pragma unroll
  for (int i = 0; i < 2; ++i)
#pragma unroll
    for (int n = 0; n < 2; ++n) oacc[i][n] = (f32x4){0.f, 0.f, 0.f, 0.f};
  float lsum[2] = {0.f, 0.f};

  char* pw = (char*)&plds[w][0];
  int swz = (l15 >> 3) << 4;                   // 1-bit XOR (row-pure, bijective)

  for (int t = 0; t < 8; ++t) {
#pragma unroll
    for (int i = 0; i < 2; ++i) {              // static unroll (rule #20)
      f32x4 sa[8];
      __builtin_amdgcn_s_setprio(1);
#pragma unroll
      for (int kn = 0; kn < 8; ++kn) {
        s16x8 kf = *(const s16x8*)(kb + (size_t)(t * 128 + kn * 16 + l15) * 32 + g * 8);
        sa[kn] = mfma16(kf, qf[i], (f32x4){0.f, 0.f, 0.f, 0.f});
      }
      __builtin_amdgcn_s_setprio(0);
      // fixed-shift numerators; lane owns query l15 (this half), keys kn*16+g*4+{0..3}
      float ps = 0.f;
#pragma unroll
      for (int kn = 0; kn < 8; ++kn) {
        float p0 = __builtin_amdgcn_exp2f(sa[kn][0] * ce - csh);
        float p1 = __builtin_amdgcn_exp2f(sa[kn][1] * ce - csh);
        float p2 = __builtin_amdgcn_exp2f(sa[kn][2] * ce - csh);
        float p3 = __builtin_amdgcn_exp2f(sa[kn][3] * ce - csh);
        ps += (p0 + p1) + (p2 + p3);
        uint2 u;
        u.x = pack2bf(p0, p1);
        u.y = pack2bf(p2, p3);
        *(s16x4*)(pw + l15 * 272 + ((kn * 32 + g * 8) ^ swz)) =
            __builtin_bit_cast(s16x4, u);
      }
      lsum[i] += ps;                           // per-lane partial; reduced at end
      // pin P-store phase before PV-read phase (same-wave LDS, no barrier needed)
      __builtin_amdgcn_sched_barrier(0);
      __builtin_amdgcn_s_setprio(1);
#pragma unroll
      for (int kk = 0; kk < 4; ++kk) {
        s16x8 pa = *(const s16x8*)(pw + l15 * 272 + ((kk * 64 + g * 16) ^ swz));
#pragma unroll
        for (int n = 0; n < 2; ++n) {
          s16x8 vf = *(const s16x8*)(vb + (size_t)(n * 16 + l15) * 1024 + t * 128 + kk * 32 + g * 8);
          oacc[i][n] = mfma16(vf, pa, oacc[i][n]);
        }
      }
      __builtin_amdgcn_s_setprio(0);
      // next half's P-stores must not move above this half's P-loads
      __builtin_amdgcn_sched_barrier(0);
    }
  }
  // final denominator: sum across the 4 g-groups (keys partition over g)
#pragma unroll
  for (int i = 0; i < 2; ++i) {
    float v = lsum[i];
    v += __shfl_xor(v, 16);
    v += __shfl_xor(v, 32);
    lsum[i] = v;
  }
  int tokq0 = b * 4096 + s * 1024 + qt * 128 + w * 32;
#pragma unroll
  for (int i = 0; i < 2; ++i) {
    float inv = 1.0f / lsum[i];
    int tok = tokq0 + i * 16 + l15;
#pragma unroll
    for (int n = 0; n < 2; ++n) {
      uint2 u;
      u.x = pack2bf(oacc[i][n][0] * inv, oacc[i][n][1] * inv);
      u.y = pack2bf(oacc[i][n][2] * inv, oacc[i][n][3] * inv);
      *(s16x4*)(ob + (size_t)tok * 384 + h * 32 + n * 16 + g * 4) =
          __builtin_bit_cast(s16x4, u);
    }
  }
}

// ---------------- launch ----------------
extern "C" void kernel_launch(void* const* d_in, const int* in_sizes, int n_in,
                              void* d_out, int out_size, void* d_ws, size_t ws_size,
                              hipStream_t stream) {
  const float* x        = (const float*)d_in[0];   // [4,4096,768]
  const float* W_reduce = (const float*)d_in[1];   // [768,384]
  const float* b_reduce = (const float*)d_in[2];   // [384]
  const float* W_qkv    = (const float*)d_in[3];   // [384,1152]
  const float* b_qkv    = (const float*)d_in[4];   // [1152]
  const float* W_proj   = (const float*)d_in[5];   // [384,768]
  const float* b_proj   = (const float*)d_in[6];   // [768]
  float* out = (float*)d_out;                      // [16384,768]

  char* ws = (char*)d_ws;
  short* wr_t    = (short*)(ws + 0);               // [384][768]    589824 B
  short* wqkv_t  = (short*)(ws + 589824);          // [1152][384]   884736 B
  short* wproj_t = (short*)(ws + 1474560);         // [768][384]    589824 B
  short* xr_b    = (short*)(ws + 2064384);         // [16384][384]  12582912 B
  short* o_b     = xr_b;                           // reuse after qkv GEMM
  short* q_p     = (short*)(ws + 14647296);        // [192][1024][32] 12582912 B
  short* k_p     = (short*)(ws + 27230208);        // 12582912 B
  short* vtok    = (short*)(ws + 39813120);        // [16384][384]  12582912 B
  short* vt      = (short*)(ws + 52396032);        // [192][32][1024] 12582912 B; ends 64978944

  // all three weight transposes in one dispatch
  transpose_cast_all<<<1008, 256, 0, stream>>>(W_reduce, wr_t, W_qkv, wqkv_t, W_proj, wproj_t);

  // xr = x @ W_reduce + b_reduce  (f32 A fused-cast, bf16 out)
  gemm_bf16<0, true><<<384, 256, 0, stream>>>(nullptr, x, wr_t, b_reduce, xr_b,
                                              nullptr, nullptr, nullptr, 16384, 384, 768);
  // qkv = xr @ W_qkv + b_qkv  -> scatter to q_p / k_p / vtok
  gemm_bf16<2, false><<<1152, 256, 0, stream>>>(xr_b, nullptr, wqkv_t, b_qkv, nullptr,
                                                q_p, k_p, vtok, 16384, 1152, 384);
  // v transpose for PV fragments
  v_transpose<<<768, 256, 0, stream>>>(vtok, vt);
  // attention -> o_b
  attn_kernel<<<1536, 256, 0, stream>>>(q_p, k_p, vt, o_b);
  // out = o @ W_proj + b_proj (f32 out)
  gemm_bf16<1, false><<<768, 256, 0, stream>>>(o_b, nullptr, wproj_t, b_proj, (void*)out,
                                               nullptr, nullptr, nullptr, 16384, 768, 384);
}

// Round 10
// 236.021 us; speedup vs baseline: 2.0320x; 1.3074x over previous
//
#include <hip/hip_runtime.h>
#include <hip/hip_bf16.h>

typedef __attribute__((ext_vector_type(8))) short   s16x8;
typedef __attribute__((ext_vector_type(4))) short   s16x4;
typedef __attribute__((ext_vector_type(8))) __bf16  bf16x8;
typedef __attribute__((ext_vector_type(4))) float   f32x4;

__device__ __forceinline__ short f2bf(float f) {
  unsigned u = __builtin_bit_cast(unsigned, f);
  u += 0x7fffu + ((u >> 16) & 1u);          // round-to-nearest-even
  return (short)(u >> 16);
}

// pack two f32 -> two bf16 in a u32 (round-half-up; bit-exact, no ISA ambiguity)
__device__ __forceinline__ unsigned pack2bf(float a, float b) {
  unsigned ua = __builtin_bit_cast(unsigned, a) + 0x8000u;
  unsigned ub = __builtin_bit_cast(unsigned, b) + 0x8000u;
  return (ua >> 16) | (ub & 0xffff0000u);
}

__device__ __forceinline__ f32x4 mfma16(s16x8 a, s16x8 b, f32x4 c) {
  return __builtin_amdgcn_mfma_f32_16x16x32_bf16(
      __builtin_bit_cast(bf16x8, a), __builtin_bit_cast(bf16x8, b), c, 0, 0, 0);
}

__device__ __forceinline__ void glds16(const short* g, short* l) {
  __builtin_amdgcn_global_load_lds(
      (__attribute__((address_space(1))) const void*)g,
      (__attribute__((address_space(3))) void*)l, 16, 0, 0);
}

// ---------------- merged transpose + cast of the 3 weights ----------------
// W_reduce 768x384 (288 blk), W_qkv 384x1152 (432 blk), W_proj 384x768 (288 blk)
__global__ __launch_bounds__(256) void transpose_cast_all(
    const float* __restrict__ s0, short* __restrict__ d0,
    const float* __restrict__ s1, short* __restrict__ d1,
    const float* __restrict__ s2, short* __restrict__ d2) {
  __shared__ float t[32 * 33];
  int id = blockIdx.x;
  const float* src; short* dst; int R, C, bx, by;
  if (id < 288)      { src = s0; dst = d0; R = 768; C = 384;  bx = id % 12;           by = id / 12; }
  else if (id < 720) { int l = id - 288; src = s1; dst = d1; R = 384; C = 1152; bx = l % 36; by = l / 36; }
  else               { int l = id - 720; src = s2; dst = d2; R = 384; C = 768;  bx = l % 24; by = l / 24; }
  int tid = threadIdx.x;
  int c0 = bx * 32, r0 = by * 32;
  for (int rep = 0; rep < 4; ++rep) {
    int idx = rep * 256 + tid;
    int rr = idx >> 5, cc = idx & 31;
    t[rr * 33 + cc] = src[(size_t)(r0 + rr) * C + c0 + cc];
  }
  __syncthreads();
  for (int rep = 0; rep < 4; ++rep) {
    int idx = rep * 256 + tid;
    int cc = idx >> 5, rr = idx & 31;
    dst[(size_t)(c0 + cc) * R + r0 + rr] = f2bf(t[rr * 33 + cc]);
  }
}

// ---------------- m97-style bf16 GEMM: A[M][K] x Bt[N][K] + bias -> out ----------------
// MODE 0: bf16 row-major out. MODE 1: f32 row-major out.
// MODE 2: qkv scatter -> q_p/k_p[bhs][1024][32] bf16, vtok[16384][384] bf16.
// AF32: A is f32 in global; reg-stage (issue early, convert+ds_write after MFMA).
template <int MODE, bool AF32>
__global__ __launch_bounds__(256, 2) void gemm_bf16(
    const short* __restrict__ A, const float* __restrict__ Af,
    const short* __restrict__ Bt,
    const float* __restrict__ bias, void* __restrict__ out,
    short* __restrict__ q_p, short* __restrict__ k_p, short* __restrict__ vtok,
    int M, int N, int K) {
  __shared__ short lds[2][2][128 * 64];
  int tid = threadIdx.x;
  int lane = tid & 63, wid = tid >> 6;
  int l15 = lane & 15, g = lane >> 4;
  int nbn = N >> 7;
  int nwg = gridDim.x;
  int bid = blockIdx.x;
  int chunk = nwg >> 3;                       // all grids are %8 == 0
  int swz_bid = (bid & 7) * chunk + (bid >> 3);
  int bm = swz_bid / nbn, bn = swz_bid % nbn;
  int wr = wid >> 1, wc = wid & 1;

  const short* Ab = AF32 ? nullptr : (A + (size_t)(bm * 128) * K);
  const float* Afb = AF32 ? (Af + (size_t)(bm * 128) * K) : nullptr;
  const short* Bb = Bt + (size_t)(bn * 128) * K;

  f32x4 acc[4][4];
#pragma unroll
  for (int i = 0; i < 4; ++i)
#pragma unroll
    for (int j = 0; j < 4; ++j) acc[i][j] = (f32x4){0.f, 0.f, 0.f, 0.f};

  f32x4 areg[4][2];                           // AF32: 8 floats per c-slot
  int nk = K >> 6;

  auto stageB = [&](int bufi, int kt) {
    const short* gb = Bb + kt * 64;
#pragma unroll
    for (int it = 0; it < 4; ++it) {
      int c = it * 256 + tid;
      int row = c >> 3, pc = c & 7;
      int lc = pc ^ (row & 7);                // pre-swizzled source (rule #21)
      glds16(gb + (size_t)row * K + lc * 8, &lds[bufi][1][(it * 256 + wid * 64) * 8]);
    }
  };
  auto stageA_lds = [&](int bufi, int kt) {
    const short* ga = Ab + kt * 64;
#pragma unroll
    for (int it = 0; it < 4; ++it) {
      int c = it * 256 + tid;
      int row = c >> 3, pc = c & 7;
      int lc = pc ^ (row & 7);
      glds16(ga + (size_t)row * K + lc * 8, &lds[bufi][0][(it * 256 + wid * 64) * 8]);
    }
  };
  auto stageA_issue = [&](int kt) {           // f32 global -> regs (no wait yet)
#pragma unroll
    for (int it = 0; it < 4; ++it) {
      int c = it * 256 + tid;
      int row = c >> 3, pc = c & 7;
      int lc = pc ^ (row & 7);
      const float* src = Afb + (size_t)row * K + kt * 64 + lc * 8;
      areg[it][0] = *(const f32x4*)(src);
      areg[it][1] = *(const f32x4*)(src + 4);
    }
  };
  auto stageA_write = [&](int bufi) {         // regs -> bf16 -> LDS (same image)
#pragma unroll
    for (int it = 0; it < 4; ++it) {
      int c = it * 256 + tid;
      s16x8 o;
#pragma unroll
      for (int q = 0; q < 4; ++q) {
        o[q]     = f2bf(areg[it][0][q]);
        o[q + 4] = f2bf(areg[it][1][q]);
      }
      *(s16x8*)(&lds[0][0][0] + ((size_t)bufi * 2 * 128 * 64) + (size_t)c * 8) = o;
    }
  };

  if (AF32) { stageA_issue(0); stageB(0, 0); stageA_write(0); }
  else      { stageA_lds(0, 0); stageB(0, 0); }
  __syncthreads();
  int buf = 0;
  for (int kt = 0; kt < nk; ++kt) {
    bool more = (kt + 1 < nk);
    if (more) {
      if (AF32) stageA_issue(kt + 1); else stageA_lds(buf ^ 1, kt + 1);
      stageB(buf ^ 1, kt + 1);
    }
    const short* la = &lds[buf][0][0];
    const short* lb = &lds[buf][1][0];
    s16x8 af[4][2], bfv[4][2];
#pragma unroll
    for (int i = 0; i < 4; ++i)
#pragma unroll
      for (int kk = 0; kk < 2; ++kk) {
        int row = wr * 64 + i * 16 + l15;
        int ch = (kk * 4 + g) ^ (l15 & 7);
        af[i][kk] = *(const s16x8*)(la + row * 64 + ch * 8);
      }
#pragma unroll
    for (int j = 0; j < 4; ++j)
#pragma unroll
      for (int kk = 0; kk < 2; ++kk) {
        int row = wc * 64 + j * 16 + l15;
        int ch = (kk * 4 + g) ^ (l15 & 7);
        bfv[j][kk] = *(const s16x8*)(lb + row * 64 + ch * 8);
      }
#pragma unroll
    for (int kk = 0; kk < 2; ++kk)
#pragma unroll
      for (int i = 0; i < 4; ++i)
#pragma unroll
        for (int j = 0; j < 4; ++j)
          acc[i][j] = mfma16(af[i][kk], bfv[j][kk], acc[i][j]);
    if (AF32 && more) stageA_write(buf ^ 1);  // HBM latency hidden under MFMA
    __syncthreads();
    buf ^= 1;
  }

#pragma unroll
  for (int j = 0; j < 4; ++j) {
    int col = bn * 128 + wc * 64 + j * 16 + l15;
    float bv = bias[col];
    int which = 0, rem = 0, h = 0, d = 0;
    if (MODE == 2) {
      which = col / 384;
      rem = col - which * 384;
      h = rem >> 5; d = rem & 31;
    }
#pragma unroll
    for (int i = 0; i < 4; ++i) {
      int row0 = bm * 128 + wr * 64 + i * 16 + g * 4;
#pragma unroll
      for (int r = 0; r < 4; ++r) {
        int row = row0 + r;
        float v = acc[i][j][r] + bv;
        if (MODE == 1) {
          ((float*)out)[(size_t)row * N + col] = v;
        } else if (MODE == 0) {
          ((short*)out)[(size_t)row * N + col] = f2bf(v);
        } else {
          short bf = f2bf(v);
          if (which == 2) {
            vtok[(size_t)row * 384 + rem] = bf;
          } else {
            int b = row >> 12, s = (row >> 10) & 3, key = row & 1023;
            size_t dst = ((size_t)((b * 12 + h) * 4 + s) << 15) + key * 32 + d;
            if (which) k_p[dst] = bf; else q_p[dst] = bf;
          }
        }
      }
    }
  }
}

// ---------------- V transpose: vtok [16384][384] -> vt[bhs][32][1024] ----------------
__global__ __launch_bounds__(256) void v_transpose(
    const short* __restrict__ vtok, short* __restrict__ vt) {
  __shared__ short t[256 * 33];
  int tid = threadIdx.x;
  int bid = blockIdx.x;                        // 192*4
  int kc = bid & 3, bhs = bid >> 2;
  int s = bhs & 3, h = (bhs >> 2) % 12, b = bhs / 48;
  int key = kc * 256 + tid;
  int tok = b * 4096 + s * 1024 + key;
  const short* src = vtok + (size_t)tok * 384 + h * 32;
#pragma unroll
  for (int c = 0; c < 4; ++c) {
    s16x8 v = *(const s16x8*)(src + c * 8);
#pragma unroll
    for (int j = 0; j < 8; ++j) t[tid * 33 + c * 8 + j] = v[j];
  }
  __syncthreads();
  int d = tid >> 3, kb = tid & 7;
  short* dst = vt + ((size_t)((b * 12 + h) * 4 + s)) * 32768 + (size_t)d * 1024 + kc * 256 + kb * 32;
#pragma unroll
  for (int cc = 0; cc < 4; ++cc) {
    s16x8 o;
#pragma unroll
    for (int j = 0; j < 8; ++j) o[j] = t[(kb * 32 + cc * 8 + j) * 33 + d];
    *(s16x8*)(dst + cc * 8) = o;
  }
}

// ---------------- flash attention: swapped QK^T, i-split + kn-split ----------------
// grid = 8 q-tiles * 192 bhs, bid = qt*192 + bhs (XCD locality on bhs).
// 4 waves * 32 q-rows; KVBLK=128; hd=32.
// i-split: the two 16-row halves run QK->softmax->PV sequentially (P buffer
// 16x272B = 4.3KB/wave, block 17.4KB).
// kn-split: QK+softmax in two passes of 4 MFMAs so only sa[4] (16 regs) of
// accumulator state is live at once; sched_barrier(0) pins pass lifetimes.
// Register budget is the lever (r8/r9 post-mortem): unified VGPR+AGPR footprint
// must stay ~<102 for 5 waves/SIMD; launch_bounds (256,2) = only spill-free cfg.
// S^T = mfma(K, Q): lane holds q = l15, keys kn*16 + g*4 + {0..3}.
// Fixed-shift softmax (validated r5); manual bf16 pack (validated r6).
__global__ __launch_bounds__(256, 2) void attn_kernel(
    const short* __restrict__ qp, const short* __restrict__ kp,
    const short* __restrict__ vt, short* __restrict__ ob) {
  __shared__ short plds[4][16 * 136];          // per-wave P[16][272B]
  int tid = threadIdx.x;
  int lane = tid & 63, w = tid >> 6;
  int l15 = lane & 15, g = lane >> 4;
  int bid = blockIdx.x;
  int bhs = bid % 192, qt = bid / 192;
  int s = bhs & 3, h = (bhs >> 2) % 12, b = bhs / 48;
  const float ce = 0.17677669529663687f * 1.4426950408889634f;  // hd^-0.5 * log2(e)
  const float csh = 12.0f * 1.4426950408889634f;                // fixed shift

  const short* qb = qp + ((size_t)bhs << 15) + (qt * 128 + w * 32) * 32;
  const short* kb = kp + ((size_t)bhs << 15);
  const short* vb = vt + ((size_t)bhs << 15);

  s16x8 qf[2];
#pragma unroll
  for (int i = 0; i < 2; ++i)
    qf[i] = *(const s16x8*)(qb + (i * 16 + l15) * 32 + g * 8);

  f32x4 oacc[2][2];
#pragma unroll
  for (int i = 0; i < 2; ++i)
#pragma unroll
    for (int n = 0; n < 2; ++n) oacc[i][n] = (f32x4){0.f, 0.f, 0.f, 0.f};
  float lsum[2] = {0.f, 0.f};

  char* pw = (char*)&plds[w][0];
  int swz = (l15 >> 3) << 4;                   // 1-bit XOR (row-pure, bijective)

  for (int t = 0; t < 8; ++t) {
#pragma unroll
    for (int i = 0; i < 2; ++i) {              // static unroll (rule #20)
#pragma unroll
      for (int kh = 0; kh < 2; ++kh) {         // kn-split: sa[4] live, not sa[8]
        f32x4 sa[4];
        __builtin_amdgcn_s_setprio(1);
#pragma unroll
        for (int k4 = 0; k4 < 4; ++k4) {
          int kn = kh * 4 + k4;
          s16x8 kf = *(const s16x8*)(kb + (size_t)(t * 128 + kn * 16 + l15) * 32 + g * 8);
          sa[k4] = mfma16(kf, qf[i], (f32x4){0.f, 0.f, 0.f, 0.f});
        }
        __builtin_amdgcn_s_setprio(0);
        // fixed-shift numerators; lane owns query l15, keys kn*16+g*4+{0..3}
        float ps = 0.f;
#pragma unroll
        for (int k4 = 0; k4 < 4; ++k4) {
          int kn = kh * 4 + k4;
          float p0 = __builtin_amdgcn_exp2f(sa[k4][0] * ce - csh);
          float p1 = __builtin_amdgcn_exp2f(sa[k4][1] * ce - csh);
          float p2 = __builtin_amdgcn_exp2f(sa[k4][2] * ce - csh);
          float p3 = __builtin_amdgcn_exp2f(sa[k4][3] * ce - csh);
          ps += (p0 + p1) + (p2 + p3);
          uint2 u;
          u.x = pack2bf(p0, p1);
          u.y = pack2bf(p2, p3);
          *(s16x4*)(pw + l15 * 272 + ((kn * 32 + g * 8) ^ swz)) =
              __builtin_bit_cast(s16x4, u);
        }
        lsum[i] += ps;                         // per-lane partial; reduced at end
        // pin this pass's lifetime: no motion across (kills sa overlap & store/load races)
        __builtin_amdgcn_sched_barrier(0);
      }
      __builtin_amdgcn_s_setprio(1);
#pragma unroll
      for (int kk = 0; kk < 4; ++kk) {
        s16x8 pa = *(const s16x8*)(pw + l15 * 272 + ((kk * 64 + g * 16) ^ swz));
#pragma unroll
        for (int n = 0; n < 2; ++n) {
          s16x8 vf = *(const s16x8*)(vb + (size_t)(n * 16 + l15) * 1024 + t * 128 + kk * 32 + g * 8);
          oacc[i][n] = mfma16(vf, pa, oacc[i][n]);
        }
      }
      __builtin_amdgcn_s_setprio(0);
      // next half's P-stores must not move above this half's P-loads
      __builtin_amdgcn_sched_barrier(0);
    }
  }
  // final denominator: sum across the 4 g-groups (keys partition over g)
#pragma unroll
  for (int i = 0; i < 2; ++i) {
    float v = lsum[i];
    v += __shfl_xor(v, 16);
    v += __shfl_xor(v, 32);
    lsum[i] = v;
  }
  int tokq0 = b * 4096 + s * 1024 + qt * 128 + w * 32;
#pragma unroll
  for (int i = 0; i < 2; ++i) {
    float inv = 1.0f / lsum[i];
    int tok = tokq0 + i * 16 + l15;
#pragma unroll
    for (int n = 0; n < 2; ++n) {
      uint2 u;
      u.x = pack2bf(oacc[i][n][0] * inv, oacc[i][n][1] * inv);
      u.y = pack2bf(oacc[i][n][2] * inv, oacc[i][n][3] * inv);
      *(s16x4*)(ob + (size_t)tok * 384 + h * 32 + n * 16 + g * 4) =
          __builtin_bit_cast(s16x4, u);
    }
  }
}

// ---------------- launch ----------------
extern "C" void kernel_launch(void* const* d_in, const int* in_sizes, int n_in,
                              void* d_out, int out_size, void* d_ws, size_t ws_size,
                              hipStream_t stream) {
  const float* x        = (const float*)d_in[0];   // [4,4096,768]
  const float* W_reduce = (const float*)d_in[1];   // [768,384]
  const float* b_reduce = (const float*)d_in[2];   // [384]
  const float* W_qkv    = (const float*)d_in[3];   // [384,1152]
  const float* b_qkv    = (const float*)d_in[4];   // [1152]
  const float* W_proj   = (const float*)d_in[5];   // [384,768]
  const float* b_proj   = (const float*)d_in[6];   // [768]
  float* out = (float*)d_out;                      // [16384,768]

  char* ws = (char*)d_ws;
  short* wr_t    = (short*)(ws + 0);               // [384][768]    589824 B
  short* wqkv_t  = (short*)(ws + 589824);          // [1152][384]   884736 B
  short* wproj_t = (short*)(ws + 1474560);         // [768][384]    589824 B
  short* xr_b    = (short*)(ws + 2064384);         // [16384][384]  12582912 B
  short* o_b     = xr_b;                           // reuse after qkv GEMM
  short* q_p     = (short*)(ws + 14647296);        // [192][1024][32] 12582912 B
  short* k_p     = (short*)(ws + 27230208);        // 12582912 B
  short* vtok    = (short*)(ws + 39813120);        // [16384][384]  12582912 B
  short* vt      = (short*)(ws + 52396032);        // [192][32][1024] 12582912 B; ends 64978944

  // all three weight transposes in one dispatch
  transpose_cast_all<<<1008, 256, 0, stream>>>(W_reduce, wr_t, W_qkv, wqkv_t, W_proj, wproj_t);

  // xr = x @ W_reduce + b_reduce  (f32 A fused-cast, bf16 out)
  gemm_bf16<0, true><<<384, 256, 0, stream>>>(nullptr, x, wr_t, b_reduce, xr_b,
                                              nullptr, nullptr, nullptr, 16384, 384, 768);
  // qkv = xr @ W_qkv + b_qkv  -> scatter to q_p / k_p / vtok
  gemm_bf16<2, false><<<1152, 256, 0, stream>>>(xr_b, nullptr, wqkv_t, b_qkv, nullptr,
                                                q_p, k_p, vtok, 16384, 1152, 384);
  // v transpose for PV fragments
  v_transpose<<<768, 256, 0, stream>>>(vtok, vt);
  // attention -> o_b
  attn_kernel<<<1536, 256, 0, stream>>>(q_p, k_p, vt, o_b);
  // out = o @ W_proj + b_proj (f32 out)
  gemm_bf16<1, false><<<768, 256, 0, stream>>>(o_b, nullptr, wproj_t, b_proj, (void*)out,
                                               nullptr, nullptr, nullptr, 16384, 768, 384);
}

// Round 11
// 179.113 us; speedup vs baseline: 2.6776x; 1.3177x over previous
//
#include <hip/hip_runtime.h>
#include <hip/hip_bf16.h>

typedef __attribute__((ext_vector_type(8))) short   s16x8;
typedef __attribute__((ext_vector_type(4))) short   s16x4;
typedef __attribute__((ext_vector_type(8))) __bf16  bf16x8;
typedef __attribute__((ext_vector_type(4))) float   f32x4;

__device__ __forceinline__ short f2bf(float f) {
  unsigned u = __builtin_bit_cast(unsigned, f);
  u += 0x7fffu + ((u >> 16) & 1u);          // round-to-nearest-even
  return (short)(u >> 16);
}

// pack two f32 -> two bf16 in a u32 (round-half-up; bit-exact, no ISA ambiguity)
__device__ __forceinline__ unsigned pack2bf(float a, float b) {
  unsigned ua = __builtin_bit_cast(unsigned, a) + 0x8000u;
  unsigned ub = __builtin_bit_cast(unsigned, b) + 0x8000u;
  return (ua >> 16) | (ub & 0xffff0000u);
}

__device__ __forceinline__ f32x4 mfma16(s16x8 a, s16x8 b, f32x4 c) {
  return __builtin_amdgcn_mfma_f32_16x16x32_bf16(
      __builtin_bit_cast(bf16x8, a), __builtin_bit_cast(bf16x8, b), c, 0, 0, 0);
}

__device__ __forceinline__ void glds16(const short* g, short* l) {
  __builtin_amdgcn_global_load_lds(
      (__attribute__((address_space(1))) const void*)g,
      (__attribute__((address_space(3))) void*)l, 16, 0, 0);
}

// ---------------- merged transpose + cast of the 3 weights ----------------
// W_reduce 768x384 (288 blk), W_qkv 384x1152 (432 blk), W_proj 384x768 (288 blk)
__global__ __launch_bounds__(256) void transpose_cast_all(
    const float* __restrict__ s0, short* __restrict__ d0,
    const float* __restrict__ s1, short* __restrict__ d1,
    const float* __restrict__ s2, short* __restrict__ d2) {
  __shared__ float t[32 * 33];
  int id = blockIdx.x;
  const float* src; short* dst; int R, C, bx, by;
  if (id < 288)      { src = s0; dst = d0; R = 768; C = 384;  bx = id % 12;           by = id / 12; }
  else if (id < 720) { int l = id - 288; src = s1; dst = d1; R = 384; C = 1152; bx = l % 36; by = l / 36; }
  else               { int l = id - 720; src = s2; dst = d2; R = 384; C = 768;  bx = l % 24; by = l / 24; }
  int tid = threadIdx.x;
  int c0 = bx * 32, r0 = by * 32;
  for (int rep = 0; rep < 4; ++rep) {
    int idx = rep * 256 + tid;
    int rr = idx >> 5, cc = idx & 31;
    t[rr * 33 + cc] = src[(size_t)(r0 + rr) * C + c0 + cc];
  }
  __syncthreads();
  for (int rep = 0; rep < 4; ++rep) {
    int idx = rep * 256 + tid;
    int cc = idx >> 5, rr = idx & 31;
    dst[(size_t)(c0 + cc) * R + r0 + rr] = f2bf(t[rr * 33 + cc]);
  }
}

// ---------------- m97-style bf16 GEMM: A[M][K] x Bt[N][K] + bias -> out ----------------
// MODE 0: bf16 row-major out. MODE 1: f32 row-major out.
// MODE 2: qkv scatter -> q_p/k_p[bhs][1024][32] bf16, vtok[16384][384] bf16.
// AF32: A is f32 in global; reg-stage (issue early, convert+ds_write after MFMA).
template <int MODE, bool AF32>
__global__ __launch_bounds__(256, 2) void gemm_bf16(
    const short* __restrict__ A, const float* __restrict__ Af,
    const short* __restrict__ Bt,
    const float* __restrict__ bias, void* __restrict__ out,
    short* __restrict__ q_p, short* __restrict__ k_p, short* __restrict__ vtok,
    int M, int N, int K) {
  __shared__ short lds[2][2][128 * 64];
  int tid = threadIdx.x;
  int lane = tid & 63, wid = tid >> 6;
  int l15 = lane & 15, g = lane >> 4;
  int nbn = N >> 7;
  int nwg = gridDim.x;
  int bid = blockIdx.x;
  int chunk = nwg >> 3;                       // all grids are %8 == 0
  int swz_bid = (bid & 7) * chunk + (bid >> 3);
  int bm = swz_bid / nbn, bn = swz_bid % nbn;
  int wr = wid >> 1, wc = wid & 1;

  const short* Ab = AF32 ? nullptr : (A + (size_t)(bm * 128) * K);
  const float* Afb = AF32 ? (Af + (size_t)(bm * 128) * K) : nullptr;
  const short* Bb = Bt + (size_t)(bn * 128) * K;

  f32x4 acc[4][4];
#pragma unroll
  for (int i = 0; i < 4; ++i)
#pragma unroll
    for (int j = 0; j < 4; ++j) acc[i][j] = (f32x4){0.f, 0.f, 0.f, 0.f};

  f32x4 areg[4][2];                           // AF32: 8 floats per c-slot
  int nk = K >> 6;

  auto stageB = [&](int bufi, int kt) {
    const short* gb = Bb + kt * 64;
#pragma unroll
    for (int it = 0; it < 4; ++it) {
      int c = it * 256 + tid;
      int row = c >> 3, pc = c & 7;
      int lc = pc ^ (row & 7);                // pre-swizzled source (rule #21)
      glds16(gb + (size_t)row * K + lc * 8, &lds[bufi][1][(it * 256 + wid * 64) * 8]);
    }
  };
  auto stageA_lds = [&](int bufi, int kt) {
    const short* ga = Ab + kt * 64;
#pragma unroll
    for (int it = 0; it < 4; ++it) {
      int c = it * 256 + tid;
      int row = c >> 3, pc = c & 7;
      int lc = pc ^ (row & 7);
      glds16(ga + (size_t)row * K + lc * 8, &lds[bufi][0][(it * 256 + wid * 64) * 8]);
    }
  };
  auto stageA_issue = [&](int kt) {           // f32 global -> regs (no wait yet)
#pragma unroll
    for (int it = 0; it < 4; ++it) {
      int c = it * 256 + tid;
      int row = c >> 3, pc = c & 7;
      int lc = pc ^ (row & 7);
      const float* src = Afb + (size_t)row * K + kt * 64 + lc * 8;
      areg[it][0] = *(const f32x4*)(src);
      areg[it][1] = *(const f32x4*)(src + 4);
    }
  };
  auto stageA_write = [&](int bufi) {         // regs -> bf16 -> LDS (same image)
#pragma unroll
    for (int it = 0; it < 4; ++it) {
      int c = it * 256 + tid;
      s16x8 o;
#pragma unroll
      for (int q = 0; q < 4; ++q) {
        o[q]     = f2bf(areg[it][0][q]);
        o[q + 4] = f2bf(areg[it][1][q]);
      }
      *(s16x8*)(&lds[0][0][0] + ((size_t)bufi * 2 * 128 * 64) + (size_t)c * 8) = o;
    }
  };

  if (AF32) { stageA_issue(0); stageB(0, 0); stageA_write(0); }
  else      { stageA_lds(0, 0); stageB(0, 0); }
  __syncthreads();
  int buf = 0;
  for (int kt = 0; kt < nk; ++kt) {
    bool more = (kt + 1 < nk);
    if (more) {
      if (AF32) stageA_issue(kt + 1); else stageA_lds(buf ^ 1, kt + 1);
      stageB(buf ^ 1, kt + 1);
    }
    const short* la = &lds[buf][0][0];
    const short* lb = &lds[buf][1][0];
    s16x8 af[4][2], bfv[4][2];
#pragma unroll
    for (int i = 0; i < 4; ++i)
#pragma unroll
      for (int kk = 0; kk < 2; ++kk) {
        int row = wr * 64 + i * 16 + l15;
        int ch = (kk * 4 + g) ^ (l15 & 7);
        af[i][kk] = *(const s16x8*)(la + row * 64 + ch * 8);
      }
#pragma unroll
    for (int j = 0; j < 4; ++j)
#pragma unroll
      for (int kk = 0; kk < 2; ++kk) {
        int row = wc * 64 + j * 16 + l15;
        int ch = (kk * 4 + g) ^ (l15 & 7);
        bfv[j][kk] = *(const s16x8*)(lb + row * 64 + ch * 8);
      }
#pragma unroll
    for (int kk = 0; kk < 2; ++kk)
#pragma unroll
      for (int i = 0; i < 4; ++i)
#pragma unroll
        for (int j = 0; j < 4; ++j)
          acc[i][j] = mfma16(af[i][kk], bfv[j][kk], acc[i][j]);
    if (AF32 && more) stageA_write(buf ^ 1);  // HBM latency hidden under MFMA
    __syncthreads();
    buf ^= 1;
  }

#pragma unroll
  for (int j = 0; j < 4; ++j) {
    int col = bn * 128 + wc * 64 + j * 16 + l15;
    float bv = bias[col];
    int which = 0, rem = 0, h = 0, d = 0;
    if (MODE == 2) {
      which = col / 384;
      rem = col - which * 384;
      h = rem >> 5; d = rem & 31;
    }
#pragma unroll
    for (int i = 0; i < 4; ++i) {
      int row0 = bm * 128 + wr * 64 + i * 16 + g * 4;
#pragma unroll
      for (int r = 0; r < 4; ++r) {
        int row = row0 + r;
        float v = acc[i][j][r] + bv;
        if (MODE == 1) {
          ((float*)out)[(size_t)row * N + col] = v;
        } else if (MODE == 0) {
          ((short*)out)[(size_t)row * N + col] = f2bf(v);
        } else {
          short bf = f2bf(v);
          if (which == 2) {
            vtok[(size_t)row * 384 + rem] = bf;
          } else {
            int b = row >> 12, s = (row >> 10) & 3, key = row & 1023;
            size_t dst = ((size_t)((b * 12 + h) * 4 + s) << 15) + key * 32 + d;
            if (which) k_p[dst] = bf; else q_p[dst] = bf;
          }
        }
      }
    }
  }
}

// ---------------- V transpose: vtok [16384][384] -> vt[bhs][32][1024] ----------------
__global__ __launch_bounds__(256) void v_transpose(
    const short* __restrict__ vtok, short* __restrict__ vt) {
  __shared__ short t[256 * 33];
  int tid = threadIdx.x;
  int bid = blockIdx.x;                        // 192*4
  int kc = bid & 3, bhs = bid >> 2;
  int s = bhs & 3, h = (bhs >> 2) % 12, b = bhs / 48;
  int key = kc * 256 + tid;
  int tok = b * 4096 + s * 1024 + key;
  const short* src = vtok + (size_t)tok * 384 + h * 32;
#pragma unroll
  for (int c = 0; c < 4; ++c) {
    s16x8 v = *(const s16x8*)(src + c * 8);
#pragma unroll
    for (int j = 0; j < 8; ++j) t[tid * 33 + c * 8 + j] = v[j];
  }
  __syncthreads();
  int d = tid >> 3, kb = tid & 7;
  short* dst = vt + ((size_t)((b * 12 + h) * 4 + s)) * 32768 + (size_t)d * 1024 + kc * 256 + kb * 32;
#pragma unroll
  for (int cc = 0; cc < 4; ++cc) {
    s16x8 o;
#pragma unroll
    for (int j = 0; j < 8; ++j) o[j] = t[(kb * 32 + cc * 8 + j) * 33 + d];
    *(s16x8*)(dst + cc * 8) = o;
  }
}

// ---------------- flash attention: swapped QK^T + fixed-shift softmax ----------------
// REVERT to the r6 structure (best measured: 90.2 us) + 2 changes:
//   (a) #pragma unroll on the kv-tile loop,
//   (b) sched_barrier mask 0x7F (ALU|VALU|SALU|MFMA|VMEM may cross; DS may not)
// so the scheduler can hoist tile t+1's K/V VMEM loads above tile t's
// softmax/PV (hiding ~300-500cy VMEM latency) while the P-store -> P-read
// DS ordering stays pinned (rule 18 / TBAA discipline).
// Occupancy quest (r8-r10) condemned: residency pinned ~2.5-3 blocks/CU
// regardless of LDS/VGPR; i-/kn-splits only lengthened the serial chain.
// grid = 8 q-tiles * 192 bhs, bid = qt*192 + bhs (XCD locality on bhs).
// S^T = mfma(K, Q): lane holds q = i*16 + l15, keys kn*16 + g*4 + {0..3}.
// P rows at 272B stride + 1-bit XOR; fixed-shift softmax (r5); manual pack (r6).
__global__ __launch_bounds__(256, 2) void attn_kernel(
    const short* __restrict__ qp, const short* __restrict__ kp,
    const short* __restrict__ vt, short* __restrict__ ob) {
  __shared__ short plds[4][32 * 136];          // per-wave P[32][272B]
  int tid = threadIdx.x;
  int lane = tid & 63, w = tid >> 6;
  int l15 = lane & 15, g = lane >> 4;
  int bid = blockIdx.x;
  int bhs = bid % 192, qt = bid / 192;
  int s = bhs & 3, h = (bhs >> 2) % 12, b = bhs / 48;
  const float ce = 0.17677669529663687f * 1.4426950408889634f;  // hd^-0.5 * log2(e)
  const float csh = 12.0f * 1.4426950408889634f;                // fixed shift

  const short* qb = qp + ((size_t)bhs << 15) + (qt * 128 + w * 32) * 32;
  const short* kb = kp + ((size_t)bhs << 15);
  const short* vb = vt + ((size_t)bhs << 15);

  s16x8 qf[2];
#pragma unroll
  for (int i = 0; i < 2; ++i)
    qf[i] = *(const s16x8*)(qb + (i * 16 + l15) * 32 + g * 8);

  f32x4 oacc[2][2];
#pragma unroll
  for (int i = 0; i < 2; ++i)
#pragma unroll
    for (int n = 0; n < 2; ++n) oacc[i][n] = (f32x4){0.f, 0.f, 0.f, 0.f};
  float lsum[2] = {0.f, 0.f};

  char* pw = (char*)&plds[w][0];
  int swz = (l15 >> 3) << 4;                   // 1-bit XOR (row-pure, bijective)

#pragma unroll
  for (int t = 0; t < 8; ++t) {
    f32x4 sa[2][8];
#pragma unroll
    for (int i = 0; i < 2; ++i)
#pragma unroll
      for (int kn = 0; kn < 8; ++kn) sa[i][kn] = (f32x4){0.f, 0.f, 0.f, 0.f};
    __builtin_amdgcn_s_setprio(1);
#pragma unroll
    for (int kn = 0; kn < 8; ++kn) {
      s16x8 kf = *(const s16x8*)(kb + (size_t)(t * 128 + kn * 16 + l15) * 32 + g * 8);
      sa[0][kn] = mfma16(kf, qf[0], sa[0][kn]);
      sa[1][kn] = mfma16(kf, qf[1], sa[1][kn]);
    }
    __builtin_amdgcn_s_setprio(0);
    // fixed-shift numerators; lane owns query i*16+l15, keys kn*16+g*4+{0..3}
#pragma unroll
    for (int i = 0; i < 2; ++i) {
      float ps = 0.f;
#pragma unroll
      for (int kn = 0; kn < 8; ++kn) {
        float p0 = __builtin_amdgcn_exp2f(sa[i][kn][0] * ce - csh);
        float p1 = __builtin_amdgcn_exp2f(sa[i][kn][1] * ce - csh);
        float p2 = __builtin_amdgcn_exp2f(sa[i][kn][2] * ce - csh);
        float p3 = __builtin_amdgcn_exp2f(sa[i][kn][3] * ce - csh);
        ps += (p0 + p1) + (p2 + p3);
        uint2 u;
        u.x = pack2bf(p0, p1);
        u.y = pack2bf(p2, p3);
        *(s16x4*)(pw + (i * 16 + l15) * 272 + ((kn * 32 + g * 8) ^ swz)) =
            __builtin_bit_cast(s16x4, u);
      }
      lsum[i] += ps;                           // per-lane partial; reduced at end
    }
    // DS-only fence: P-stores stay before PV P-loads; VALU/VMEM/MFMA may cross
    __builtin_amdgcn_sched_barrier(0x7F);
    __builtin_amdgcn_s_setprio(1);
#pragma unroll
    for (int kk = 0; kk < 4; ++kk) {
      s16x8 pa[2];
#pragma unroll
      for (int i = 0; i < 2; ++i)
        pa[i] = *(const s16x8*)(pw + (i * 16 + l15) * 272 + ((kk * 64 + g * 16) ^ swz));
#pragma unroll
      for (int n = 0; n < 2; ++n) {
        s16x8 vf = *(const s16x8*)(vb + (size_t)(n * 16 + l15) * 1024 + t * 128 + kk * 32 + g * 8);
        oacc[0][n] = mfma16(vf, pa[0], oacc[0][n]);
        oacc[1][n] = mfma16(vf, pa[1], oacc[1][n]);
      }
    }
    __builtin_amdgcn_s_setprio(0);
    // DS-only fence: next tile's P-stores stay after this tile's P-loads
    __builtin_amdgcn_sched_barrier(0x7F);
  }
  // final denominator: sum across the 4 g-groups (keys partition over g)
#pragma unroll
  for (int i = 0; i < 2; ++i) {
    float v = lsum[i];
    v += __shfl_xor(v, 16);
    v += __shfl_xor(v, 32);
    lsum[i] = v;
  }
  int tokq0 = b * 4096 + s * 1024 + qt * 128 + w * 32;
#pragma unroll
  for (int i = 0; i < 2; ++i) {
    float inv = 1.0f / lsum[i];
    int tok = tokq0 + i * 16 + l15;
#pragma unroll
    for (int n = 0; n < 2; ++n) {
      uint2 u;
      u.x = pack2bf(oacc[i][n][0] * inv, oacc[i][n][1] * inv);
      u.y = pack2bf(oacc[i][n][2] * inv, oacc[i][n][3] * inv);
      *(s16x4*)(ob + (size_t)tok * 384 + h * 32 + n * 16 + g * 4) =
          __builtin_bit_cast(s16x4, u);
    }
  }
}

// ---------------- launch ----------------
extern "C" void kernel_launch(void* const* d_in, const int* in_sizes, int n_in,
                              void* d_out, int out_size, void* d_ws, size_t ws_size,
                              hipStream_t stream) {
  const float* x        = (const float*)d_in[0];   // [4,4096,768]
  const float* W_reduce = (const float*)d_in[1];   // [768,384]
  const float* b_reduce = (const float*)d_in[2];   // [384]
  const float* W_qkv    = (const float*)d_in[3];   // [384,1152]
  const float* b_qkv    = (const float*)d_in[4];   // [1152]
  const float* W_proj   = (const float*)d_in[5];   // [384,768]
  const float* b_proj   = (const float*)d_in[6];   // [768]
  float* out = (float*)d_out;                      // [16384,768]

  char* ws = (char*)d_ws;
  short* wr_t    = (short*)(ws + 0);               // [384][768]    589824 B
  short* wqkv_t  = (short*)(ws + 589824);          // [1152][384]   884736 B
  short* wproj_t = (short*)(ws + 1474560);         // [768][384]    589824 B
  short* xr_b    = (short*)(ws + 2064384);         // [16384][384]  12582912 B
  short* o_b     = xr_b;                           // reuse after qkv GEMM
  short* q_p     = (short*)(ws + 14647296);        // [192][1024][32] 12582912 B
  short* k_p     = (short*)(ws + 27230208);        // 12582912 B
  short* vtok    = (short*)(ws + 39813120);        // [16384][384]  12582912 B
  short* vt      = (short*)(ws + 52396032);        // [192][32][1024] 12582912 B; ends 64978944

  // all three weight transposes in one dispatch
  transpose_cast_all<<<1008, 256, 0, stream>>>(W_reduce, wr_t, W_qkv, wqkv_t, W_proj, wproj_t);

  // xr = x @ W_reduce + b_reduce  (f32 A fused-cast, bf16 out)
  gemm_bf16<0, true><<<384, 256, 0, stream>>>(nullptr, x, wr_t, b_reduce, xr_b,
                                              nullptr, nullptr, nullptr, 16384, 384, 768);
  // qkv = xr @ W_qkv + b_qkv  -> scatter to q_p / k_p / vtok
  gemm_bf16<2, false><<<1152, 256, 0, stream>>>(xr_b, nullptr, wqkv_t, b_qkv, nullptr,
                                                q_p, k_p, vtok, 16384, 1152, 384);
  // v transpose for PV fragments
  v_transpose<<<768, 256, 0, stream>>>(vtok, vt);
  // attention -> o_b
  attn_kernel<<<1536, 256, 0, stream>>>(q_p, k_p, vt, o_b);
  // out = o @ W_proj + b_proj (f32 out)
  gemm_bf16<1, false><<<768, 256, 0, stream>>>(o_b, nullptr, wproj_t, b_proj, (void*)out,
                                               nullptr, nullptr, nullptr, 16384, 768, 384);
}

// Round 12
// 166.612 us; speedup vs baseline: 2.8785x; 1.0750x over previous
//
#include <hip/hip_runtime.h>
#include <hip/hip_bf16.h>

typedef __attribute__((ext_vector_type(8))) short   s16x8;
typedef __attribute__((ext_vector_type(4))) short   s16x4;
typedef __attribute__((ext_vector_type(8))) __bf16  bf16x8;
typedef __attribute__((ext_vector_type(4))) float   f32x4;

__device__ __forceinline__ short f2bf(float f) {
  unsigned u = __builtin_bit_cast(unsigned, f);
  u += 0x7fffu + ((u >> 16) & 1u);          // round-to-nearest-even
  return (short)(u >> 16);
}

// pack two f32 -> two bf16 in a u32 (round-half-up; bit-exact, no ISA ambiguity)
__device__ __forceinline__ unsigned pack2bf(float a, float b) {
  unsigned ua = __builtin_bit_cast(unsigned, a) + 0x8000u;
  unsigned ub = __builtin_bit_cast(unsigned, b) + 0x8000u;
  return (ua >> 16) | (ub & 0xffff0000u);
}

__device__ __forceinline__ f32x4 mfma16(s16x8 a, s16x8 b, f32x4 c) {
  return __builtin_amdgcn_mfma_f32_16x16x32_bf16(
      __builtin_bit_cast(bf16x8, a), __builtin_bit_cast(bf16x8, b), c, 0, 0, 0);
}

__device__ __forceinline__ void glds16(const short* g, short* l) {
  __builtin_amdgcn_global_load_lds(
      (__attribute__((address_space(1))) const void*)g,
      (__attribute__((address_space(3))) void*)l, 16, 0, 0);
}

// ---------------- merged transpose + cast of the 3 weights ----------------
// W_reduce 768x384 (288 blk), W_qkv 384x1152 (432 blk), W_proj 384x768 (288 blk)
__global__ __launch_bounds__(256) void transpose_cast_all(
    const float* __restrict__ s0, short* __restrict__ d0,
    const float* __restrict__ s1, short* __restrict__ d1,
    const float* __restrict__ s2, short* __restrict__ d2) {
  __shared__ float t[32 * 33];
  int id = blockIdx.x;
  const float* src; short* dst; int R, C, bx, by;
  if (id < 288)      { src = s0; dst = d0; R = 768; C = 384;  bx = id % 12;           by = id / 12; }
  else if (id < 720) { int l = id - 288; src = s1; dst = d1; R = 384; C = 1152; bx = l % 36; by = l / 36; }
  else               { int l = id - 720; src = s2; dst = d2; R = 384; C = 768;  bx = l % 24; by = l / 24; }
  int tid = threadIdx.x;
  int c0 = bx * 32, r0 = by * 32;
  for (int rep = 0; rep < 4; ++rep) {
    int idx = rep * 256 + tid;
    int rr = idx >> 5, cc = idx & 31;
    t[rr * 33 + cc] = src[(size_t)(r0 + rr) * C + c0 + cc];
  }
  __syncthreads();
  for (int rep = 0; rep < 4; ++rep) {
    int idx = rep * 256 + tid;
    int cc = idx >> 5, rr = idx & 31;
    dst[(size_t)(c0 + cc) * R + r0 + rr] = f2bf(t[rr * 33 + cc]);
  }
}

// ---------------- m97-style bf16 GEMM: A[M][K] x Bt[N][K] + bias -> out ----------------
// MODE 0: bf16 row-major out. MODE 1: f32 row-major out.
// MODE 2: qkv scatter -> q_p/k_p[bhs][1024][32] bf16, vtok[16384][384] bf16.
// AF32: A is f32 in global; reg-stage (issue early, convert+ds_write after MFMA).
template <int MODE, bool AF32>
__global__ __launch_bounds__(256, 2) void gemm_bf16(
    const short* __restrict__ A, const float* __restrict__ Af,
    const short* __restrict__ Bt,
    const float* __restrict__ bias, void* __restrict__ out,
    short* __restrict__ q_p, short* __restrict__ k_p, short* __restrict__ vtok,
    int M, int N, int K) {
  __shared__ short lds[2][2][128 * 64];
  int tid = threadIdx.x;
  int lane = tid & 63, wid = tid >> 6;
  int l15 = lane & 15, g = lane >> 4;
  int nbn = N >> 7;
  int nwg = gridDim.x;
  int bid = blockIdx.x;
  int chunk = nwg >> 3;                       // all grids are %8 == 0
  int swz_bid = (bid & 7) * chunk + (bid >> 3);
  int bm = swz_bid / nbn, bn = swz_bid % nbn;
  int wr = wid >> 1, wc = wid & 1;

  const short* Ab = AF32 ? nullptr : (A + (size_t)(bm * 128) * K);
  const float* Afb = AF32 ? (Af + (size_t)(bm * 128) * K) : nullptr;
  const short* Bb = Bt + (size_t)(bn * 128) * K;

  f32x4 acc[4][4];
#pragma unroll
  for (int i = 0; i < 4; ++i)
#pragma unroll
    for (int j = 0; j < 4; ++j) acc[i][j] = (f32x4){0.f, 0.f, 0.f, 0.f};

  f32x4 areg[4][2];                           // AF32: 8 floats per c-slot
  int nk = K >> 6;

  auto stageB = [&](int bufi, int kt) {
    const short* gb = Bb + kt * 64;
#pragma unroll
    for (int it = 0; it < 4; ++it) {
      int c = it * 256 + tid;
      int row = c >> 3, pc = c & 7;
      int lc = pc ^ (row & 7);                // pre-swizzled source (rule #21)
      glds16(gb + (size_t)row * K + lc * 8, &lds[bufi][1][(it * 256 + wid * 64) * 8]);
    }
  };
  auto stageA_lds = [&](int bufi, int kt) {
    const short* ga = Ab + kt * 64;
#pragma unroll
    for (int it = 0; it < 4; ++it) {
      int c = it * 256 + tid;
      int row = c >> 3, pc = c & 7;
      int lc = pc ^ (row & 7);
      glds16(ga + (size_t)row * K + lc * 8, &lds[bufi][0][(it * 256 + wid * 64) * 8]);
    }
  };
  auto stageA_issue = [&](int kt) {           // f32 global -> regs (no wait yet)
#pragma unroll
    for (int it = 0; it < 4; ++it) {
      int c = it * 256 + tid;
      int row = c >> 3, pc = c & 7;
      int lc = pc ^ (row & 7);
      const float* src = Afb + (size_t)row * K + kt * 64 + lc * 8;
      areg[it][0] = *(const f32x4*)(src);
      areg[it][1] = *(const f32x4*)(src + 4);
    }
  };
  auto stageA_write = [&](int bufi) {         // regs -> bf16 -> LDS (same image)
#pragma unroll
    for (int it = 0; it < 4; ++it) {
      int c = it * 256 + tid;
      s16x8 o;
#pragma unroll
      for (int q = 0; q < 4; ++q) {
        o[q]     = f2bf(areg[it][0][q]);
        o[q + 4] = f2bf(areg[it][1][q]);
      }
      *(s16x8*)(&lds[0][0][0] + ((size_t)bufi * 2 * 128 * 64) + (size_t)c * 8) = o;
    }
  };

  if (AF32) { stageA_issue(0); stageB(0, 0); stageA_write(0); }
  else      { stageA_lds(0, 0); stageB(0, 0); }
  __syncthreads();
  int buf = 0;
  for (int kt = 0; kt < nk; ++kt) {
    bool more = (kt + 1 < nk);
    if (more) {
      if (AF32) stageA_issue(kt + 1); else stageA_lds(buf ^ 1, kt + 1);
      stageB(buf ^ 1, kt + 1);
    }
    const short* la = &lds[buf][0][0];
    const short* lb = &lds[buf][1][0];
    s16x8 af[4][2], bfv[4][2];
#pragma unroll
    for (int i = 0; i < 4; ++i)
#pragma unroll
      for (int kk = 0; kk < 2; ++kk) {
        int row = wr * 64 + i * 16 + l15;
        int ch = (kk * 4 + g) ^ (l15 & 7);
        af[i][kk] = *(const s16x8*)(la + row * 64 + ch * 8);
      }
#pragma unroll
    for (int j = 0; j < 4; ++j)
#pragma unroll
      for (int kk = 0; kk < 2; ++kk) {
        int row = wc * 64 + j * 16 + l15;
        int ch = (kk * 4 + g) ^ (l15 & 7);
        bfv[j][kk] = *(const s16x8*)(lb + row * 64 + ch * 8);
      }
#pragma unroll
    for (int kk = 0; kk < 2; ++kk)
#pragma unroll
      for (int i = 0; i < 4; ++i)
#pragma unroll
        for (int j = 0; j < 4; ++j)
          acc[i][j] = mfma16(af[i][kk], bfv[j][kk], acc[i][j]);
    if (AF32 && more) stageA_write(buf ^ 1);  // HBM latency hidden under MFMA
    __syncthreads();
    buf ^= 1;
  }

#pragma unroll
  for (int j = 0; j < 4; ++j) {
    int col = bn * 128 + wc * 64 + j * 16 + l15;
    float bv = bias[col];
    int which = 0, rem = 0, h = 0, d = 0;
    if (MODE == 2) {
      which = col / 384;
      rem = col - which * 384;
      h = rem >> 5; d = rem & 31;
    }
#pragma unroll
    for (int i = 0; i < 4; ++i) {
      int row0 = bm * 128 + wr * 64 + i * 16 + g * 4;
#pragma unroll
      for (int r = 0; r < 4; ++r) {
        int row = row0 + r;
        float v = acc[i][j][r] + bv;
        if (MODE == 1) {
          ((float*)out)[(size_t)row * N + col] = v;
        } else if (MODE == 0) {
          ((short*)out)[(size_t)row * N + col] = f2bf(v);
        } else {
          short bf = f2bf(v);
          if (which == 2) {
            vtok[(size_t)row * 384 + rem] = bf;
          } else {
            int b = row >> 12, s = (row >> 10) & 3, key = row & 1023;
            size_t dst = ((size_t)((b * 12 + h) * 4 + s) << 15) + key * 32 + d;
            if (which) k_p[dst] = bf; else q_p[dst] = bf;
          }
        }
      }
    }
  }
}

// ---------------- V transpose: vtok [16384][384] -> vt[bhs][32][1024] ----------------
__global__ __launch_bounds__(256) void v_transpose(
    const short* __restrict__ vtok, short* __restrict__ vt) {
  __shared__ short t[256 * 33];
  int tid = threadIdx.x;
  int bid = blockIdx.x;                        // 192*4
  int kc = bid & 3, bhs = bid >> 2;
  int s = bhs & 3, h = (bhs >> 2) % 12, b = bhs / 48;
  int key = kc * 256 + tid;
  int tok = b * 4096 + s * 1024 + key;
  const short* src = vtok + (size_t)tok * 384 + h * 32;
#pragma unroll
  for (int c = 0; c < 4; ++c) {
    s16x8 v = *(const s16x8*)(src + c * 8);
#pragma unroll
    for (int j = 0; j < 8; ++j) t[tid * 33 + c * 8 + j] = v[j];
  }
  __syncthreads();
  int d = tid >> 3, kb = tid & 7;
  short* dst = vt + ((size_t)((b * 12 + h) * 4 + s)) * 32768 + (size_t)d * 1024 + kc * 256 + kb * 32;
#pragma unroll
  for (int cc = 0; cc < 4; ++cc) {
    s16x8 o;
#pragma unroll
    for (int j = 0; j < 8; ++j) o[j] = t[(kb * 32 + cc * 8 + j) * 33 + d];
    *(s16x8*)(dst + cc * 8) = o;
  }
}

// ---------------- flash attention: swapped QK^T + fixed-shift softmax ----------------
// EXACT r6 structure (best measured: 90.2 us, VGPR 60) with ONE change:
//   sched_barrier mask 0 -> 0x7F (ALU|VALU|SALU|MFMA|VMEM may cross; DS may not)
// so V-fragment VMEM loads can hoist above the softmax phase (covering their
// ~200-400cy L2 latency under the exp2/pack VALU block) while the
// P-store -> P-read DS ordering stays pinned (rule 18 / TBAA discipline).
// NO t-loop unroll: r11 showed unroll pushes VGPR 60->116 (past the 64-VGPR
// occupancy cliff, m69) and loses more than the fence gains.
// grid = 8 q-tiles * 192 bhs, bid = qt*192 + bhs (XCD locality on bhs).
// S^T = mfma(K, Q): lane holds q = i*16 + l15, keys kn*16 + g*4 + {0..3}.
// P rows at 272B stride + 1-bit XOR; fixed-shift softmax (r5); manual pack (r6).
__global__ __launch_bounds__(256, 2) void attn_kernel(
    const short* __restrict__ qp, const short* __restrict__ kp,
    const short* __restrict__ vt, short* __restrict__ ob) {
  __shared__ short plds[4][32 * 136];          // per-wave P[32][272B]
  int tid = threadIdx.x;
  int lane = tid & 63, w = tid >> 6;
  int l15 = lane & 15, g = lane >> 4;
  int bid = blockIdx.x;
  int bhs = bid % 192, qt = bid / 192;
  int s = bhs & 3, h = (bhs >> 2) % 12, b = bhs / 48;
  const float ce = 0.17677669529663687f * 1.4426950408889634f;  // hd^-0.5 * log2(e)
  const float csh = 12.0f * 1.4426950408889634f;                // fixed shift

  const short* qb = qp + ((size_t)bhs << 15) + (qt * 128 + w * 32) * 32;
  const short* kb = kp + ((size_t)bhs << 15);
  const short* vb = vt + ((size_t)bhs << 15);

  s16x8 qf[2];
#pragma unroll
  for (int i = 0; i < 2; ++i)
    qf[i] = *(const s16x8*)(qb + (i * 16 + l15) * 32 + g * 8);

  f32x4 oacc[2][2];
#pragma unroll
  for (int i = 0; i < 2; ++i)
#pragma unroll
    for (int n = 0; n < 2; ++n) oacc[i][n] = (f32x4){0.f, 0.f, 0.f, 0.f};
  float lsum[2] = {0.f, 0.f};

  char* pw = (char*)&plds[w][0];
  int swz = (l15 >> 3) << 4;                   // 1-bit XOR (row-pure, bijective)

  for (int t = 0; t < 8; ++t) {
    f32x4 sa[2][8];
#pragma unroll
    for (int i = 0; i < 2; ++i)
#pragma unroll
      for (int kn = 0; kn < 8; ++kn) sa[i][kn] = (f32x4){0.f, 0.f, 0.f, 0.f};
    __builtin_amdgcn_s_setprio(1);
#pragma unroll
    for (int kn = 0; kn < 8; ++kn) {
      s16x8 kf = *(const s16x8*)(kb + (size_t)(t * 128 + kn * 16 + l15) * 32 + g * 8);
      sa[0][kn] = mfma16(kf, qf[0], sa[0][kn]);
      sa[1][kn] = mfma16(kf, qf[1], sa[1][kn]);
    }
    __builtin_amdgcn_s_setprio(0);
    // fixed-shift numerators; lane owns query i*16+l15, keys kn*16+g*4+{0..3}
#pragma unroll
    for (int i = 0; i < 2; ++i) {
      float ps = 0.f;
#pragma unroll
      for (int kn = 0; kn < 8; ++kn) {
        float p0 = __builtin_amdgcn_exp2f(sa[i][kn][0] * ce - csh);
        float p1 = __builtin_amdgcn_exp2f(sa[i][kn][1] * ce - csh);
        float p2 = __builtin_amdgcn_exp2f(sa[i][kn][2] * ce - csh);
        float p3 = __builtin_amdgcn_exp2f(sa[i][kn][3] * ce - csh);
        ps += (p0 + p1) + (p2 + p3);
        uint2 u;
        u.x = pack2bf(p0, p1);
        u.y = pack2bf(p2, p3);
        *(s16x4*)(pw + (i * 16 + l15) * 272 + ((kn * 32 + g * 8) ^ swz)) =
            __builtin_bit_cast(s16x4, u);
      }
      lsum[i] += ps;                           // per-lane partial; reduced at end
    }
    // DS-only fence: P-stores stay before PV P-loads; VALU/VMEM/MFMA may cross
    // (lets the scheduler hoist this tile's V-fragment loads above the softmax)
    __builtin_amdgcn_sched_barrier(0x7F);
    __builtin_amdgcn_s_setprio(1);
#pragma unroll
    for (int kk = 0; kk < 4; ++kk) {
      s16x8 pa[2];
#pragma unroll
      for (int i = 0; i < 2; ++i)
        pa[i] = *(const s16x8*)(pw + (i * 16 + l15) * 272 + ((kk * 64 + g * 16) ^ swz));
#pragma unroll
      for (int n = 0; n < 2; ++n) {
        s16x8 vf = *(const s16x8*)(vb + (size_t)(n * 16 + l15) * 1024 + t * 128 + kk * 32 + g * 8);
        oacc[0][n] = mfma16(vf, pa[0], oacc[0][n]);
        oacc[1][n] = mfma16(vf, pa[1], oacc[1][n]);
      }
    }
    __builtin_amdgcn_s_setprio(0);
    // DS-only fence: next tile's P-stores stay after this tile's P-loads
    __builtin_amdgcn_sched_barrier(0x7F);
  }
  // final denominator: sum across the 4 g-groups (keys partition over g)
#pragma unroll
  for (int i = 0; i < 2; ++i) {
    float v = lsum[i];
    v += __shfl_xor(v, 16);
    v += __shfl_xor(v, 32);
    lsum[i] = v;
  }
  int tokq0 = b * 4096 + s * 1024 + qt * 128 + w * 32;
#pragma unroll
  for (int i = 0; i < 2; ++i) {
    float inv = 1.0f / lsum[i];
    int tok = tokq0 + i * 16 + l15;
#pragma unroll
    for (int n = 0; n < 2; ++n) {
      uint2 u;
      u.x = pack2bf(oacc[i][n][0] * inv, oacc[i][n][1] * inv);
      u.y = pack2bf(oacc[i][n][2] * inv, oacc[i][n][3] * inv);
      *(s16x4*)(ob + (size_t)tok * 384 + h * 32 + n * 16 + g * 4) =
          __builtin_bit_cast(s16x4, u);
    }
  }
}

// ---------------- launch ----------------
extern "C" void kernel_launch(void* const* d_in, const int* in_sizes, int n_in,
                              void* d_out, int out_size, void* d_ws, size_t ws_size,
                              hipStream_t stream) {
  const float* x        = (const float*)d_in[0];   // [4,4096,768]
  const float* W_reduce = (const float*)d_in[1];   // [768,384]
  const float* b_reduce = (const float*)d_in[2];   // [384]
  const float* W_qkv    = (const float*)d_in[3];   // [384,1152]
  const float* b_qkv    = (const float*)d_in[4];   // [1152]
  const float* W_proj   = (const float*)d_in[5];   // [384,768]
  const float* b_proj   = (const float*)d_in[6];   // [768]
  float* out = (float*)d_out;                      // [16384,768]

  char* ws = (char*)d_ws;
  short* wr_t    = (short*)(ws + 0);               // [384][768]    589824 B
  short* wqkv_t  = (short*)(ws + 589824);          // [1152][384]   884736 B
  short* wproj_t = (short*)(ws + 1474560);         // [768][384]    589824 B
  short* xr_b    = (short*)(ws + 2064384);         // [16384][384]  12582912 B
  short* o_b     = xr_b;                           // reuse after qkv GEMM
  short* q_p     = (short*)(ws + 14647296);        // [192][1024][32] 12582912 B
  short* k_p     = (short*)(ws + 27230208);        // 12582912 B
  short* vtok    = (short*)(ws + 39813120);        // [16384][384]  12582912 B
  short* vt      = (short*)(ws + 52396032);        // [192][32][1024] 12582912 B; ends 64978944

  // all three weight transposes in one dispatch
  transpose_cast_all<<<1008, 256, 0, stream>>>(W_reduce, wr_t, W_qkv, wqkv_t, W_proj, wproj_t);

  // xr = x @ W_reduce + b_reduce  (f32 A fused-cast, bf16 out)
  gemm_bf16<0, true><<<384, 256, 0, stream>>>(nullptr, x, wr_t, b_reduce, xr_b,
                                              nullptr, nullptr, nullptr, 16384, 384, 768);
  // qkv = xr @ W_qkv + b_qkv  -> scatter to q_p / k_p / vtok
  gemm_bf16<2, false><<<1152, 256, 0, stream>>>(xr_b, nullptr, wqkv_t, b_qkv, nullptr,
                                                q_p, k_p, vtok, 16384, 1152, 384);
  // v transpose for PV fragments
  v_transpose<<<768, 256, 0, stream>>>(vtok, vt);
  // attention -> o_b
  attn_kernel<<<1536, 256, 0, stream>>>(q_p, k_p, vt, o_b);
  // out = o @ W_proj + b_proj (f32 out)
  gemm_bf16<1, false><<<768, 256, 0, stream>>>(o_b, nullptr, wproj_t, b_proj, (void*)out,
                                               nullptr, nullptr, nullptr, 16384, 768, 384);
}

// Round 14
// 164.188 us; speedup vs baseline: 2.9210x; 1.0148x over previous
//
#include <hip/hip_runtime.h>
#include <hip/hip_bf16.h>

typedef __attribute__((ext_vector_type(8))) short   s16x8;
typedef __attribute__((ext_vector_type(4))) short   s16x4;
typedef __attribute__((ext_vector_type(8))) __bf16  bf16x8;
typedef __attribute__((ext_vector_type(4))) float   f32x4;

__device__ __forceinline__ short f2bf(float f) {
  unsigned u = __builtin_bit_cast(unsigned, f);
  u += 0x7fffu + ((u >> 16) & 1u);          // round-to-nearest-even
  return (short)(u >> 16);
}

// two f32 -> packed bf16 pair via hardware packed cvt (m240: let the compiler
// emit it from the HIP conversion API; manual bit-ops hide it). memcpy because
// __hip_bfloat162 is not trivially copyable (bit_cast rejected, r13).
__device__ __forceinline__ unsigned cvt2bf(float a, float b) {
  __hip_bfloat162 r = __float22bfloat162_rn(make_float2(a, b));
  unsigned u;
  __builtin_memcpy(&u, &r, 4);
  return u;
}

__device__ __forceinline__ f32x4 mfma16(s16x8 a, s16x8 b, f32x4 c) {
  return __builtin_amdgcn_mfma_f32_16x16x32_bf16(
      __builtin_bit_cast(bf16x8, a), __builtin_bit_cast(bf16x8, b), c, 0, 0, 0);
}

__device__ __forceinline__ void glds16(const short* g, short* l) {
  __builtin_amdgcn_global_load_lds(
      (__attribute__((address_space(1))) const void*)g,
      (__attribute__((address_space(3))) void*)l, 16, 0, 0);
}

// ---------------- merged transpose + cast of the 3 weights ----------------
// W_reduce 768x384 (288 blk), W_qkv 384x1152 (432 blk), W_proj 384x768 (288 blk)
__global__ __launch_bounds__(256) void transpose_cast_all(
    const float* __restrict__ s0, short* __restrict__ d0,
    const float* __restrict__ s1, short* __restrict__ d1,
    const float* __restrict__ s2, short* __restrict__ d2) {
  __shared__ float t[32 * 33];
  int id = blockIdx.x;
  const float* src; short* dst; int R, C, bx, by;
  if (id < 288)      { src = s0; dst = d0; R = 768; C = 384;  bx = id % 12;           by = id / 12; }
  else if (id < 720) { int l = id - 288; src = s1; dst = d1; R = 384; C = 1152; bx = l % 36; by = l / 36; }
  else               { int l = id - 720; src = s2; dst = d2; R = 384; C = 768;  bx = l % 24; by = l / 24; }
  int tid = threadIdx.x;
  int c0 = bx * 32, r0 = by * 32;
  for (int rep = 0; rep < 4; ++rep) {
    int idx = rep * 256 + tid;
    int rr = idx >> 5, cc = idx & 31;
    t[rr * 33 + cc] = src[(size_t)(r0 + rr) * C + c0 + cc];
  }
  __syncthreads();
  for (int rep = 0; rep < 4; ++rep) {
    int idx = rep * 256 + tid;
    int cc = idx >> 5, rr = idx & 31;
    dst[(size_t)(c0 + cc) * R + r0 + rr] = f2bf(t[rr * 33 + cc]);
  }
}

// ---------------- m97-style bf16 GEMM: A[M][K] x Bt[N][K] + bias -> out ----------------
// MODE 0: bf16 row-major out. MODE 1: f32 row-major out.
// MODE 2: qkv scatter -> q_p/k_p[bhs][1024][32] bf16, vtok[16384][384] bf16.
//   q-part is pre-scaled by hd^-0.5*log2e so attn scores come out in log2 units
//   (the softmax fixed shift cancels in the p/lsum ratio and is dropped).
// AF32: A is f32 in global; reg-stage (issue early, convert+ds_write after MFMA).
template <int MODE, bool AF32>
__global__ __launch_bounds__(256, 2) void gemm_bf16(
    const short* __restrict__ A, const float* __restrict__ Af,
    const short* __restrict__ Bt,
    const float* __restrict__ bias, void* __restrict__ out,
    short* __restrict__ q_p, short* __restrict__ k_p, short* __restrict__ vtok,
    int M, int N, int K) {
  __shared__ short lds[2][2][128 * 64];
  int tid = threadIdx.x;
  int lane = tid & 63, wid = tid >> 6;
  int l15 = lane & 15, g = lane >> 4;
  int nbn = N >> 7;
  int nwg = gridDim.x;
  int bid = blockIdx.x;
  int chunk = nwg >> 3;                       // all grids are %8 == 0
  int swz_bid = (bid & 7) * chunk + (bid >> 3);
  int bm = swz_bid / nbn, bn = swz_bid % nbn;
  int wr = wid >> 1, wc = wid & 1;

  const short* Ab = AF32 ? nullptr : (A + (size_t)(bm * 128) * K);
  const float* Afb = AF32 ? (Af + (size_t)(bm * 128) * K) : nullptr;
  const short* Bb = Bt + (size_t)(bn * 128) * K;

  f32x4 acc[4][4];
#pragma unroll
  for (int i = 0; i < 4; ++i)
#pragma unroll
    for (int j = 0; j < 4; ++j) acc[i][j] = (f32x4){0.f, 0.f, 0.f, 0.f};

  f32x4 areg[4][2];                           // AF32: 8 floats per c-slot
  int nk = K >> 6;

  auto stageB = [&](int bufi, int kt) {
    const short* gb = Bb + kt * 64;
#pragma unroll
    for (int it = 0; it < 4; ++it) {
      int c = it * 256 + tid;
      int row = c >> 3, pc = c & 7;
      int lc = pc ^ (row & 7);                // pre-swizzled source (rule #21)
      glds16(gb + (size_t)row * K + lc * 8, &lds[bufi][1][(it * 256 + wid * 64) * 8]);
    }
  };
  auto stageA_lds = [&](int bufi, int kt) {
    const short* ga = Ab + kt * 64;
#pragma unroll
    for (int it = 0; it < 4; ++it) {
      int c = it * 256 + tid;
      int row = c >> 3, pc = c & 7;
      int lc = pc ^ (row & 7);
      glds16(ga + (size_t)row * K + lc * 8, &lds[bufi][0][(it * 256 + wid * 64) * 8]);
    }
  };
  auto stageA_issue = [&](int kt) {           // f32 global -> regs (no wait yet)
#pragma unroll
    for (int it = 0; it < 4; ++it) {
      int c = it * 256 + tid;
      int row = c >> 3, pc = c & 7;
      int lc = pc ^ (row & 7);
      const float* src = Afb + (size_t)row * K + kt * 64 + lc * 8;
      areg[it][0] = *(const f32x4*)(src);
      areg[it][1] = *(const f32x4*)(src + 4);
    }
  };
  auto stageA_write = [&](int bufi) {         // regs -> bf16 -> LDS (same image)
#pragma unroll
    for (int it = 0; it < 4; ++it) {
      int c = it * 256 + tid;
      s16x8 o;
#pragma unroll
      for (int q = 0; q < 4; ++q) {
        o[q]     = f2bf(areg[it][0][q]);
        o[q + 4] = f2bf(areg[it][1][q]);
      }
      *(s16x8*)(&lds[0][0][0] + ((size_t)bufi * 2 * 128 * 64) + (size_t)c * 8) = o;
    }
  };

  if (AF32) { stageA_issue(0); stageB(0, 0); stageA_write(0); }
  else      { stageA_lds(0, 0); stageB(0, 0); }
  __syncthreads();
  int buf = 0;
  for (int kt = 0; kt < nk; ++kt) {
    bool more = (kt + 1 < nk);
    if (more) {
      if (AF32) stageA_issue(kt + 1); else stageA_lds(buf ^ 1, kt + 1);
      stageB(buf ^ 1, kt + 1);
    }
    const short* la = &lds[buf][0][0];
    const short* lb = &lds[buf][1][0];
    s16x8 af[4][2], bfv[4][2];
#pragma unroll
    for (int i = 0; i < 4; ++i)
#pragma unroll
      for (int kk = 0; kk < 2; ++kk) {
        int row = wr * 64 + i * 16 + l15;
        int ch = (kk * 4 + g) ^ (l15 & 7);
        af[i][kk] = *(const s16x8*)(la + row * 64 + ch * 8);
      }
#pragma unroll
    for (int j = 0; j < 4; ++j)
#pragma unroll
      for (int kk = 0; kk < 2; ++kk) {
        int row = wc * 64 + j * 16 + l15;
        int ch = (kk * 4 + g) ^ (l15 & 7);
        bfv[j][kk] = *(const s16x8*)(lb + row * 64 + ch * 8);
      }
#pragma unroll
    for (int kk = 0; kk < 2; ++kk)
#pragma unroll
      for (int i = 0; i < 4; ++i)
#pragma unroll
        for (int j = 0; j < 4; ++j)
          acc[i][j] = mfma16(af[i][kk], bfv[j][kk], acc[i][j]);
    if (AF32 && more) stageA_write(buf ^ 1);  // HBM latency hidden under MFMA
    __syncthreads();
    buf ^= 1;
  }

#pragma unroll
  for (int j = 0; j < 4; ++j) {
    int col = bn * 128 + wc * 64 + j * 16 + l15;
    float bv = bias[col];
    int which = 0, rem = 0, h = 0, d = 0;
    if (MODE == 2) {
      which = col / 384;
      rem = col - which * 384;
      h = rem >> 5; d = rem & 31;
    }
#pragma unroll
    for (int i = 0; i < 4; ++i) {
      int row0 = bm * 128 + wr * 64 + i * 16 + g * 4;
#pragma unroll
      for (int r = 0; r < 4; ++r) {
        int row = row0 + r;
        float v = acc[i][j][r] + bv;
        if (MODE == 1) {
          ((float*)out)[(size_t)row * N + col] = v;
        } else if (MODE == 0) {
          ((short*)out)[(size_t)row * N + col] = f2bf(v);
        } else {
          // fold hd^-0.5 * log2(e) into q so attn scores are in log2 units
          if (which == 0) v *= (0.17677669529663687f * 1.4426950408889634f);
          short bf = f2bf(v);
          if (which == 2) {
            vtok[(size_t)row * 384 + rem] = bf;
          } else {
            int b = row >> 12, s = (row >> 10) & 3, key = row & 1023;
            size_t dst = ((size_t)((b * 12 + h) * 4 + s) << 15) + key * 32 + d;
            if (which) k_p[dst] = bf; else q_p[dst] = bf;
          }
        }
      }
    }
  }
}

// ---------------- V transpose: vtok [16384][384] -> vt[bhs][32][1024] ----------------
__global__ __launch_bounds__(256) void v_transpose(
    const short* __restrict__ vtok, short* __restrict__ vt) {
  __shared__ short t[256 * 33];
  int tid = threadIdx.x;
  int bid = blockIdx.x;                        // 192*4
  int kc = bid & 3, bhs = bid >> 2;
  int s = bhs & 3, h = (bhs >> 2) % 12, b = bhs / 48;
  int key = kc * 256 + tid;
  int tok = b * 4096 + s * 1024 + key;
  const short* src = vtok + (size_t)tok * 384 + h * 32;
#pragma unroll
  for (int c = 0; c < 4; ++c) {
    s16x8 v = *(const s16x8*)(src + c * 8);
#pragma unroll
    for (int j = 0; j < 8; ++j) t[tid * 33 + c * 8 + j] = v[j];
  }
  __syncthreads();
  int d = tid >> 3, kb = tid & 7;
  short* dst = vt + ((size_t)((b * 12 + h) * 4 + s)) * 32768 + (size_t)d * 1024 + kc * 256 + kb * 32;
#pragma unroll
  for (int cc = 0; cc < 4; ++cc) {
    s16x8 o;
#pragma unroll
    for (int j = 0; j < 8; ++j) o[j] = t[(kb * 32 + cc * 8 + j) * 33 + d];
    *(s16x8*)(dst + cc * 8) = o;
  }
}

// ---------------- flash attention: swapped QK^T, VALU-diet softmax ----------------
// r12 structure (90.2 us) with the softmax VALU cut (r12 post-mortem: pack2bf
// was 5 ops/pair x 32 + 64 fma = ~220 of ~300 VALU ops/lane/tile):
//   - q pre-scaled by hd^-0.5*log2e in the qkv epilogue -> scores in log2 units
//   - fixed shift dropped (cancels in p/lsum ratio) -> p = exp2(sa), no fma
//   - P and output packed via __float22bfloat162_rn -> hw packed cvt
// grid = 8 q-tiles * 192 bhs, bid = qt*192 + bhs (XCD locality on bhs).
// S^T = mfma(K, Q): lane holds q = i*16 + l15, keys kn*16 + g*4 + {0..3}.
// P rows at 272B stride + 1-bit XOR; DS-only fences (0x7F) pin the P round-trip.
__global__ __launch_bounds__(256, 2) void attn_kernel(
    const short* __restrict__ qp, const short* __restrict__ kp,
    const short* __restrict__ vt, short* __restrict__ ob) {
  __shared__ short plds[4][32 * 136];          // per-wave P[32][272B]
  int tid = threadIdx.x;
  int lane = tid & 63, w = tid >> 6;
  int l15 = lane & 15, g = lane >> 4;
  int bid = blockIdx.x;
  int bhs = bid % 192, qt = bid / 192;
  int s = bhs & 3, h = (bhs >> 2) % 12, b = bhs / 48;

  const short* qb = qp + ((size_t)bhs << 15) + (qt * 128 + w * 32) * 32;
  const short* kb = kp + ((size_t)bhs << 15);
  const short* vb = vt + ((size_t)bhs << 15);

  s16x8 qf[2];
#pragma unroll
  for (int i = 0; i < 2; ++i)
    qf[i] = *(const s16x8*)(qb + (i * 16 + l15) * 32 + g * 8);

  f32x4 oacc[2][2];
#pragma unroll
  for (int i = 0; i < 2; ++i)
#pragma unroll
    for (int n = 0; n < 2; ++n) oacc[i][n] = (f32x4){0.f, 0.f, 0.f, 0.f};
  float lsum[2] = {0.f, 0.f};

  char* pw = (char*)&plds[w][0];
  int swz = (l15 >> 3) << 4;                   // 1-bit XOR (row-pure, bijective)

  for (int t = 0; t < 8; ++t) {
    f32x4 sa[2][8];
#pragma unroll
    for (int i = 0; i < 2; ++i)
#pragma unroll
      for (int kn = 0; kn < 8; ++kn) sa[i][kn] = (f32x4){0.f, 0.f, 0.f, 0.f};
    __builtin_amdgcn_s_setprio(1);
#pragma unroll
    for (int kn = 0; kn < 8; ++kn) {
      s16x8 kf = *(const s16x8*)(kb + (size_t)(t * 128 + kn * 16 + l15) * 32 + g * 8);
      sa[0][kn] = mfma16(kf, qf[0], sa[0][kn]);
      sa[1][kn] = mfma16(kf, qf[1], sa[1][kn]);
    }
    __builtin_amdgcn_s_setprio(0);
    // numerators: p = exp2(sa) directly (q pre-scaled; shift cancels in ratio)
#pragma unroll
    for (int i = 0; i < 2; ++i) {
      float ps = 0.f;
#pragma unroll
      for (int kn = 0; kn < 8; ++kn) {
        float p0 = __builtin_amdgcn_exp2f(sa[i][kn][0]);
        float p1 = __builtin_amdgcn_exp2f(sa[i][kn][1]);
        float p2 = __builtin_amdgcn_exp2f(sa[i][kn][2]);
        float p3 = __builtin_amdgcn_exp2f(sa[i][kn][3]);
        ps += (p0 + p1) + (p2 + p3);
        uint2 u;
        u.x = cvt2bf(p0, p1);
        u.y = cvt2bf(p2, p3);
        *(s16x4*)(pw + (i * 16 + l15) * 272 + ((kn * 32 + g * 8) ^ swz)) =
            __builtin_bit_cast(s16x4, u);
      }
      lsum[i] += ps;                           // per-lane partial; reduced at end
    }
    // DS-only fence: P-stores stay before PV P-loads; VALU/VMEM/MFMA may cross
    __builtin_amdgcn_sched_barrier(0x7F);
    __builtin_amdgcn_s_setprio(1);
#pragma unroll
    for (int kk = 0; kk < 4; ++kk) {
      s16x8 pa[2];
#pragma unroll
      for (int i = 0; i < 2; ++i)
        pa[i] = *(const s16x8*)(pw + (i * 16 + l15) * 272 + ((kk * 64 + g * 16) ^ swz));
#pragma unroll
      for (int n = 0; n < 2; ++n) {
        s16x8 vf = *(const s16x8*)(vb + (size_t)(n * 16 + l15) * 1024 + t * 128 + kk * 32 + g * 8);
        oacc[0][n] = mfma16(vf, pa[0], oacc[0][n]);
        oacc[1][n] = mfma16(vf, pa[1], oacc[1][n]);
      }
    }
    __builtin_amdgcn_s_setprio(0);
    // DS-only fence: next tile's P-stores stay after this tile's P-loads
    __builtin_amdgcn_sched_barrier(0x7F);
  }
  // final denominator: sum across the 4 g-groups (keys partition over g)
#pragma unroll
  for (int i = 0; i < 2; ++i) {
    float v = lsum[i];
    v += __shfl_xor(v, 16);
    v += __shfl_xor(v, 32);
    lsum[i] = v;
  }
  int tokq0 = b * 4096 + s * 1024 + qt * 128 + w * 32;
#pragma unroll
  for (int i = 0; i < 2; ++i) {
    float inv = 1.0f / lsum[i];
    int tok = tokq0 + i * 16 + l15;
#pragma unroll
    for (int n = 0; n < 2; ++n) {
      uint2 u;
      u.x = cvt2bf(oacc[i][n][0] * inv, oacc[i][n][1] * inv);
      u.y = cvt2bf(oacc[i][n][2] * inv, oacc[i][n][3] * inv);
      *(s16x4*)(ob + (size_t)tok * 384 + h * 32 + n * 16 + g * 4) =
          __builtin_bit_cast(s16x4, u);
    }
  }
}

// ---------------- launch ----------------
extern "C" void kernel_launch(void* const* d_in, const int* in_sizes, int n_in,
                              void* d_out, int out_size, void* d_ws, size_t ws_size,
                              hipStream_t stream) {
  const float* x        = (const float*)d_in[0];   // [4,4096,768]
  const float* W_reduce = (const float*)d_in[1];   // [768,384]
  const float* b_reduce = (const float*)d_in[2];   // [384]
  const float* W_qkv    = (const float*)d_in[3];   // [384,1152]
  const float* b_qkv    = (const float*)d_in[4];   // [1152]
  const float* W_proj   = (const float*)d_in[5];   // [384,768]
  const float* b_proj   = (const float*)d_in[6];   // [768]
  float* out = (float*)d_out;                      // [16384,768]

  char* ws = (char*)d_ws;
  short* wr_t    = (short*)(ws + 0);               // [384][768]    589824 B
  short* wqkv_t  = (short*)(ws + 589824);          // [1152][384]   884736 B
  short* wproj_t = (short*)(ws + 1474560);         // [768][384]    589824 B
  short* xr_b    = (short*)(ws + 2064384);         // [16384][384]  12582912 B
  short* o_b     = xr_b;                           // reuse after qkv GEMM
  short* q_p     = (short*)(ws + 14647296);        // [192][1024][32] 12582912 B
  short* k_p     = (short*)(ws + 27230208);        // 12582912 B
  short* vtok    = (short*)(ws + 39813120);        // [16384][384]  12582912 B
  short* vt      = (short*)(ws + 52396032);        // [192][32][1024] 12582912 B; ends 64978944

  // all three weight transposes in one dispatch
  transpose_cast_all<<<1008, 256, 0, stream>>>(W_reduce, wr_t, W_qkv, wqkv_t, W_proj, wproj_t);

  // xr = x @ W_reduce + b_reduce  (f32 A fused-cast, bf16 out)
  gemm_bf16<0, true><<<384, 256, 0, stream>>>(nullptr, x, wr_t, b_reduce, xr_b,
                                              nullptr, nullptr, nullptr, 16384, 384, 768);
  // qkv = xr @ W_qkv + b_qkv  -> scatter to q_p / k_p / vtok (q pre-scaled)
  gemm_bf16<2, false><<<1152, 256, 0, stream>>>(xr_b, nullptr, wqkv_t, b_qkv, nullptr,
                                                q_p, k_p, vtok, 16384, 1152, 384);
  // v transpose for PV fragments
  v_transpose<<<768, 256, 0, stream>>>(vtok, vt);
  // attention -> o_b
  attn_kernel<<<1536, 256, 0, stream>>>(q_p, k_p, vt, o_b);
  // out = o @ W_proj + b_proj (f32 out)
  gemm_bf16<1, false><<<768, 256, 0, stream>>>(o_b, nullptr, wproj_t, b_proj, (void*)out,
                                               nullptr, nullptr, nullptr, 16384, 768, 384);
}

// Round 15
// 162.832 us; speedup vs baseline: 2.9453x; 1.0083x over previous
//
#include <hip/hip_runtime.h>
#include <hip/hip_bf16.h>

typedef __attribute__((ext_vector_type(8))) short   s16x8;
typedef __attribute__((ext_vector_type(4))) short   s16x4;
typedef __attribute__((ext_vector_type(8))) __bf16  bf16x8;
typedef __attribute__((ext_vector_type(4))) float   f32x4;

__device__ __forceinline__ short f2bf(float f) {
  unsigned u = __builtin_bit_cast(unsigned, f);
  u += 0x7fffu + ((u >> 16) & 1u);          // round-to-nearest-even
  return (short)(u >> 16);
}

// two f32 -> packed bf16 pair via hardware packed cvt (m240: let the compiler
// emit it from the HIP conversion API; manual bit-ops hide it). memcpy because
// __hip_bfloat162 is not trivially copyable (bit_cast rejected, r13).
__device__ __forceinline__ unsigned cvt2bf(float a, float b) {
  __hip_bfloat162 r = __float22bfloat162_rn(make_float2(a, b));
  unsigned u;
  __builtin_memcpy(&u, &r, 4);
  return u;
}

__device__ __forceinline__ f32x4 mfma16(s16x8 a, s16x8 b, f32x4 c) {
  return __builtin_amdgcn_mfma_f32_16x16x32_bf16(
      __builtin_bit_cast(bf16x8, a), __builtin_bit_cast(bf16x8, b), c, 0, 0, 0);
}

__device__ __forceinline__ void glds16(const short* g, short* l) {
  __builtin_amdgcn_global_load_lds(
      (__attribute__((address_space(1))) const void*)g,
      (__attribute__((address_space(3))) void*)l, 16, 0, 0);
}

// ---------------- merged transpose + cast of the 3 weights ----------------
// W_reduce 768x384 (288 blk), W_qkv 384x1152 (432 blk), W_proj 384x768 (288 blk)
__global__ __launch_bounds__(256) void transpose_cast_all(
    const float* __restrict__ s0, short* __restrict__ d0,
    const float* __restrict__ s1, short* __restrict__ d1,
    const float* __restrict__ s2, short* __restrict__ d2) {
  __shared__ float t[32 * 33];
  int id = blockIdx.x;
  const float* src; short* dst; int R, C, bx, by;
  if (id < 288)      { src = s0; dst = d0; R = 768; C = 384;  bx = id % 12;           by = id / 12; }
  else if (id < 720) { int l = id - 288; src = s1; dst = d1; R = 384; C = 1152; bx = l % 36; by = l / 36; }
  else               { int l = id - 720; src = s2; dst = d2; R = 384; C = 768;  bx = l % 24; by = l / 24; }
  int tid = threadIdx.x;
  int c0 = bx * 32, r0 = by * 32;
  for (int rep = 0; rep < 4; ++rep) {
    int idx = rep * 256 + tid;
    int rr = idx >> 5, cc = idx & 31;
    t[rr * 33 + cc] = src[(size_t)(r0 + rr) * C + c0 + cc];
  }
  __syncthreads();
  for (int rep = 0; rep < 4; ++rep) {
    int idx = rep * 256 + tid;
    int cc = idx >> 5, rr = idx & 31;
    dst[(size_t)(c0 + cc) * R + r0 + rr] = f2bf(t[rr * 33 + cc]);
  }
}

// ---------------- m97-style bf16 GEMM: A[M][K] x Bt[N][K] + bias -> out ----------------
// MODE 0: bf16 row-major out. MODE 1: f32 row-major out.
// MODE 2: qkv scatter -> q_p/k_p[bhs][1024][32] bf16, vtok[16384][384] bf16.
//   q-part is pre-scaled by hd^-0.5*log2e so attn scores come out in log2 units
//   (the softmax fixed shift cancels in the p/lsum ratio and is dropped).
// AF32: A is f32 in global; reg-stage (issue early, convert+ds_write after MFMA).
template <int MODE, bool AF32>
__global__ __launch_bounds__(256, 2) void gemm_bf16(
    const short* __restrict__ A, const float* __restrict__ Af,
    const short* __restrict__ Bt,
    const float* __restrict__ bias, void* __restrict__ out,
    short* __restrict__ q_p, short* __restrict__ k_p, short* __restrict__ vtok,
    int M, int N, int K) {
  __shared__ short lds[2][2][128 * 64];
  int tid = threadIdx.x;
  int lane = tid & 63, wid = tid >> 6;
  int l15 = lane & 15, g = lane >> 4;
  int nbn = N >> 7;
  int nwg = gridDim.x;
  int bid = blockIdx.x;
  int chunk = nwg >> 3;                       // all grids are %8 == 0
  int swz_bid = (bid & 7) * chunk + (bid >> 3);
  int bm = swz_bid / nbn, bn = swz_bid % nbn;
  int wr = wid >> 1, wc = wid & 1;

  const short* Ab = AF32 ? nullptr : (A + (size_t)(bm * 128) * K);
  const float* Afb = AF32 ? (Af + (size_t)(bm * 128) * K) : nullptr;
  const short* Bb = Bt + (size_t)(bn * 128) * K;

  f32x4 acc[4][4];
#pragma unroll
  for (int i = 0; i < 4; ++i)
#pragma unroll
    for (int j = 0; j < 4; ++j) acc[i][j] = (f32x4){0.f, 0.f, 0.f, 0.f};

  f32x4 areg[4][2];                           // AF32: 8 floats per c-slot
  int nk = K >> 6;

  auto stageB = [&](int bufi, int kt) {
    const short* gb = Bb + kt * 64;
#pragma unroll
    for (int it = 0; it < 4; ++it) {
      int c = it * 256 + tid;
      int row = c >> 3, pc = c & 7;
      int lc = pc ^ (row & 7);                // pre-swizzled source (rule #21)
      glds16(gb + (size_t)row * K + lc * 8, &lds[bufi][1][(it * 256 + wid * 64) * 8]);
    }
  };
  auto stageA_lds = [&](int bufi, int kt) {
    const short* ga = Ab + kt * 64;
#pragma unroll
    for (int it = 0; it < 4; ++it) {
      int c = it * 256 + tid;
      int row = c >> 3, pc = c & 7;
      int lc = pc ^ (row & 7);
      glds16(ga + (size_t)row * K + lc * 8, &lds[bufi][0][(it * 256 + wid * 64) * 8]);
    }
  };
  auto stageA_issue = [&](int kt) {           // f32 global -> regs (no wait yet)
#pragma unroll
    for (int it = 0; it < 4; ++it) {
      int c = it * 256 + tid;
      int row = c >> 3, pc = c & 7;
      int lc = pc ^ (row & 7);
      const float* src = Afb + (size_t)row * K + kt * 64 + lc * 8;
      areg[it][0] = *(const f32x4*)(src);
      areg[it][1] = *(const f32x4*)(src + 4);
    }
  };
  auto stageA_write = [&](int bufi) {         // regs -> bf16 -> LDS (same image)
#pragma unroll
    for (int it = 0; it < 4; ++it) {
      int c = it * 256 + tid;
      s16x8 o;
#pragma unroll
      for (int q = 0; q < 4; ++q) {
        o[q]     = f2bf(areg[it][0][q]);
        o[q + 4] = f2bf(areg[it][1][q]);
      }
      *(s16x8*)(&lds[0][0][0] + ((size_t)bufi * 2 * 128 * 64) + (size_t)c * 8) = o;
    }
  };

  if (AF32) { stageA_issue(0); stageB(0, 0); stageA_write(0); }
  else      { stageA_lds(0, 0); stageB(0, 0); }
  __syncthreads();
  int buf = 0;
  for (int kt = 0; kt < nk; ++kt) {
    bool more = (kt + 1 < nk);
    if (more) {
      if (AF32) stageA_issue(kt + 1); else stageA_lds(buf ^ 1, kt + 1);
      stageB(buf ^ 1, kt + 1);
    }
    const short* la = &lds[buf][0][0];
    const short* lb = &lds[buf][1][0];
    s16x8 af[4][2], bfv[4][2];
#pragma unroll
    for (int i = 0; i < 4; ++i)
#pragma unroll
      for (int kk = 0; kk < 2; ++kk) {
        int row = wr * 64 + i * 16 + l15;
        int ch = (kk * 4 + g) ^ (l15 & 7);
        af[i][kk] = *(const s16x8*)(la + row * 64 + ch * 8);
      }
#pragma unroll
    for (int j = 0; j < 4; ++j)
#pragma unroll
      for (int kk = 0; kk < 2; ++kk) {
        int row = wc * 64 + j * 16 + l15;
        int ch = (kk * 4 + g) ^ (l15 & 7);
        bfv[j][kk] = *(const s16x8*)(lb + row * 64 + ch * 8);
      }
#pragma unroll
    for (int kk = 0; kk < 2; ++kk)
#pragma unroll
      for (int i = 0; i < 4; ++i)
#pragma unroll
        for (int j = 0; j < 4; ++j)
          acc[i][j] = mfma16(af[i][kk], bfv[j][kk], acc[i][j]);
    if (AF32 && more) stageA_write(buf ^ 1);  // HBM latency hidden under MFMA
    __syncthreads();
    buf ^= 1;
  }

#pragma unroll
  for (int j = 0; j < 4; ++j) {
    int col = bn * 128 + wc * 64 + j * 16 + l15;
    float bv = bias[col];
    int which = 0, rem = 0, h = 0, d = 0;
    if (MODE == 2) {
      which = col / 384;
      rem = col - which * 384;
      h = rem >> 5; d = rem & 31;
    }
#pragma unroll
    for (int i = 0; i < 4; ++i) {
      int row0 = bm * 128 + wr * 64 + i * 16 + g * 4;
#pragma unroll
      for (int r = 0; r < 4; ++r) {
        int row = row0 + r;
        float v = acc[i][j][r] + bv;
        if (MODE == 1) {
          ((float*)out)[(size_t)row * N + col] = v;
        } else if (MODE == 0) {
          ((short*)out)[(size_t)row * N + col] = f2bf(v);
        } else {
          // fold hd^-0.5 * log2(e) into q so attn scores are in log2 units
          if (which == 0) v *= (0.17677669529663687f * 1.4426950408889634f);
          short bf = f2bf(v);
          if (which == 2) {
            vtok[(size_t)row * 384 + rem] = bf;
          } else {
            int b = row >> 12, s = (row >> 10) & 3, key = row & 1023;
            size_t dst = ((size_t)((b * 12 + h) * 4 + s) << 15) + key * 32 + d;
            if (which) k_p[dst] = bf; else q_p[dst] = bf;
          }
        }
      }
    }
  }
}

// ---------------- V transpose: vtok [16384][384] -> vt[bhs][32][1024] ----------------
__global__ __launch_bounds__(256) void v_transpose(
    const short* __restrict__ vtok, short* __restrict__ vt) {
  __shared__ short t[256 * 33];
  int tid = threadIdx.x;
  int bid = blockIdx.x;                        // 192*4
  int kc = bid & 3, bhs = bid >> 2;
  int s = bhs & 3, h = (bhs >> 2) % 12, b = bhs / 48;
  int key = kc * 256 + tid;
  int tok = b * 4096 + s * 1024 + key;
  const short* src = vtok + (size_t)tok * 384 + h * 32;
#pragma unroll
  for (int c = 0; c < 4; ++c) {
    s16x8 v = *(const s16x8*)(src + c * 8);
#pragma unroll
    for (int j = 0; j < 8; ++j) t[tid * 33 + c * 8 + j] = v[j];
  }
  __syncthreads();
  int d = tid >> 3, kb = tid & 7;
  short* dst = vt + ((size_t)((b * 12 + h) * 4 + s)) * 32768 + (size_t)d * 1024 + kc * 256 + kb * 32;
#pragma unroll
  for (int cc = 0; cc < 4; ++cc) {
    s16x8 o;
#pragma unroll
    for (int j = 0; j < 8; ++j) o[j] = t[(kb * 32 + cc * 8 + j) * 33 + d];
    *(s16x8*)(dst + cc * 8) = o;
  }
}

// ---------------- flash attention: swapped QK^T, 2-wave blocks ----------------
// r14 per-wave body byte-identical; ONLY the block geometry changes:
// 2 waves/block (64 q-rows), grid 3072 = 16 q-tiles * 192 bhs.
// Rationale (r14 post-mortem): no pipe saturated (VALU 33%, MFMA 12%, HBM 6%),
// occupancy pinned ~2.6 blocks/CU by the 34.8KB LDS of 4-wave blocks; each wave
// is stalled ~87% of wall. Halving the block halves LDS/block (17.4KB -> 9
// blocks/CU by LDS) and doubles schedulable block slots -> ~2x waves/CU to
// cover the per-wave serial chain (QK -> exp2 -> P roundtrip -> PV).
// XCD locality preserved: bid%8 = bhs%8 (192%8==0).
// S^T = mfma(K, Q): lane holds q = i*16 + l15, keys kn*16 + g*4 + {0..3}.
// P rows at 272B stride + 1-bit XOR; DS-only fences (0x7F) pin the P round-trip.
__global__ __launch_bounds__(128, 2) void attn_kernel(
    const short* __restrict__ qp, const short* __restrict__ kp,
    const short* __restrict__ vt, short* __restrict__ ob) {
  __shared__ short plds[2][32 * 136];          // per-wave P[32][272B]
  int tid = threadIdx.x;
  int lane = tid & 63, w = tid >> 6;           // w in {0,1}
  int l15 = lane & 15, g = lane >> 4;
  int bid = blockIdx.x;
  int bhs = bid % 192, qt = bid / 192;         // qt in 0..15, 64 q-rows each
  int s = bhs & 3, h = (bhs >> 2) % 12, b = bhs / 48;

  const short* qb = qp + ((size_t)bhs << 15) + (qt * 64 + w * 32) * 32;
  const short* kb = kp + ((size_t)bhs << 15);
  const short* vb = vt + ((size_t)bhs << 15);

  s16x8 qf[2];
#pragma unroll
  for (int i = 0; i < 2; ++i)
    qf[i] = *(const s16x8*)(qb + (i * 16 + l15) * 32 + g * 8);

  f32x4 oacc[2][2];
#pragma unroll
  for (int i = 0; i < 2; ++i)
#pragma unroll
    for (int n = 0; n < 2; ++n) oacc[i][n] = (f32x4){0.f, 0.f, 0.f, 0.f};
  float lsum[2] = {0.f, 0.f};

  char* pw = (char*)&plds[w][0];
  int swz = (l15 >> 3) << 4;                   // 1-bit XOR (row-pure, bijective)

  for (int t = 0; t < 8; ++t) {
    f32x4 sa[2][8];
#pragma unroll
    for (int i = 0; i < 2; ++i)
#pragma unroll
      for (int kn = 0; kn < 8; ++kn) sa[i][kn] = (f32x4){0.f, 0.f, 0.f, 0.f};
    __builtin_amdgcn_s_setprio(1);
#pragma unroll
    for (int kn = 0; kn < 8; ++kn) {
      s16x8 kf = *(const s16x8*)(kb + (size_t)(t * 128 + kn * 16 + l15) * 32 + g * 8);
      sa[0][kn] = mfma16(kf, qf[0], sa[0][kn]);
      sa[1][kn] = mfma16(kf, qf[1], sa[1][kn]);
    }
    __builtin_amdgcn_s_setprio(0);
    // numerators: p = exp2(sa) directly (q pre-scaled; shift cancels in ratio)
#pragma unroll
    for (int i = 0; i < 2; ++i) {
      float ps = 0.f;
#pragma unroll
      for (int kn = 0; kn < 8; ++kn) {
        float p0 = __builtin_amdgcn_exp2f(sa[i][kn][0]);
        float p1 = __builtin_amdgcn_exp2f(sa[i][kn][1]);
        float p2 = __builtin_amdgcn_exp2f(sa[i][kn][2]);
        float p3 = __builtin_amdgcn_exp2f(sa[i][kn][3]);
        ps += (p0 + p1) + (p2 + p3);
        uint2 u;
        u.x = cvt2bf(p0, p1);
        u.y = cvt2bf(p2, p3);
        *(s16x4*)(pw + (i * 16 + l15) * 272 + ((kn * 32 + g * 8) ^ swz)) =
            __builtin_bit_cast(s16x4, u);
      }
      lsum[i] += ps;                           // per-lane partial; reduced at end
    }
    // DS-only fence: P-stores stay before PV P-loads; VALU/VMEM/MFMA may cross
    __builtin_amdgcn_sched_barrier(0x7F);
    __builtin_amdgcn_s_setprio(1);
#pragma unroll
    for (int kk = 0; kk < 4; ++kk) {
      s16x8 pa[2];
#pragma unroll
      for (int i = 0; i < 2; ++i)
        pa[i] = *(const s16x8*)(pw + (i * 16 + l15) * 272 + ((kk * 64 + g * 16) ^ swz));
#pragma unroll
      for (int n = 0; n < 2; ++n) {
        s16x8 vf = *(const s16x8*)(vb + (size_t)(n * 16 + l15) * 1024 + t * 128 + kk * 32 + g * 8);
        oacc[0][n] = mfma16(vf, pa[0], oacc[0][n]);
        oacc[1][n] = mfma16(vf, pa[1], oacc[1][n]);
      }
    }
    __builtin_amdgcn_s_setprio(0);
    // DS-only fence: next tile's P-stores stay after this tile's P-loads
    __builtin_amdgcn_sched_barrier(0x7F);
  }
  // final denominator: sum across the 4 g-groups (keys partition over g)
#pragma unroll
  for (int i = 0; i < 2; ++i) {
    float v = lsum[i];
    v += __shfl_xor(v, 16);
    v += __shfl_xor(v, 32);
    lsum[i] = v;
  }
  int tokq0 = b * 4096 + s * 1024 + qt * 64 + w * 32;
#pragma unroll
  for (int i = 0; i < 2; ++i) {
    float inv = 1.0f / lsum[i];
    int tok = tokq0 + i * 16 + l15;
#pragma unroll
    for (int n = 0; n < 2; ++n) {
      uint2 u;
      u.x = cvt2bf(oacc[i][n][0] * inv, oacc[i][n][1] * inv);
      u.y = cvt2bf(oacc[i][n][2] * inv, oacc[i][n][3] * inv);
      *(s16x4*)(ob + (size_t)tok * 384 + h * 32 + n * 16 + g * 4) =
          __builtin_bit_cast(s16x4, u);
    }
  }
}

// ---------------- launch ----------------
extern "C" void kernel_launch(void* const* d_in, const int* in_sizes, int n_in,
                              void* d_out, int out_size, void* d_ws, size_t ws_size,
                              hipStream_t stream) {
  const float* x        = (const float*)d_in[0];   // [4,4096,768]
  const float* W_reduce = (const float*)d_in[1];   // [768,384]
  const float* b_reduce = (const float*)d_in[2];   // [384]
  const float* W_qkv    = (const float*)d_in[3];   // [384,1152]
  const float* b_qkv    = (const float*)d_in[4];   // [1152]
  const float* W_proj   = (const float*)d_in[5];   // [384,768]
  const float* b_proj   = (const float*)d_in[6];   // [768]
  float* out = (float*)d_out;                      // [16384,768]

  char* ws = (char*)d_ws;
  short* wr_t    = (short*)(ws + 0);               // [384][768]    589824 B
  short* wqkv_t  = (short*)(ws + 589824);          // [1152][384]   884736 B
  short* wproj_t = (short*)(ws + 1474560);         // [768][384]    589824 B
  short* xr_b    = (short*)(ws + 2064384);         // [16384][384]  12582912 B
  short* o_b     = xr_b;                           // reuse after qkv GEMM
  short* q_p     = (short*)(ws + 14647296);        // [192][1024][32] 12582912 B
  short* k_p     = (short*)(ws + 27230208);        // 12582912 B
  short* vtok    = (short*)(ws + 39813120);        // [16384][384]  12582912 B
  short* vt      = (short*)(ws + 52396032);        // [192][32][1024] 12582912 B; ends 64978944

  // all three weight transposes in one dispatch
  transpose_cast_all<<<1008, 256, 0, stream>>>(W_reduce, wr_t, W_qkv, wqkv_t, W_proj, wproj_t);

  // xr = x @ W_reduce + b_reduce  (f32 A fused-cast, bf16 out)
  gemm_bf16<0, true><<<384, 256, 0, stream>>>(nullptr, x, wr_t, b_reduce, xr_b,
                                              nullptr, nullptr, nullptr, 16384, 384, 768);
  // qkv = xr @ W_qkv + b_qkv  -> scatter to q_p / k_p / vtok (q pre-scaled)
  gemm_bf16<2, false><<<1152, 256, 0, stream>>>(xr_b, nullptr, wqkv_t, b_qkv, nullptr,
                                                q_p, k_p, vtok, 16384, 1152, 384);
  // v transpose for PV fragments
  v_transpose<<<768, 256, 0, stream>>>(vtok, vt);
  // attention -> o_b  (2-wave blocks, 16 q-tiles per bhs)
  attn_kernel<<<3072, 128, 0, stream>>>(q_p, k_p, vt, o_b);
  // out = o @ W_proj + b_proj (f32 out)
  gemm_bf16<1, false><<<768, 256, 0, stream>>>(o_b, nullptr, wproj_t, b_proj, (void*)out,
                                               nullptr, nullptr, nullptr, 16384, 768, 384);
}

// Round 16
// 159.920 us; speedup vs baseline: 2.9989x; 1.0182x over previous
//
#include <hip/hip_runtime.h>
#include <hip/hip_bf16.h>

typedef __attribute__((ext_vector_type(8))) short   s16x8;
typedef __attribute__((ext_vector_type(4))) short   s16x4;
typedef __attribute__((ext_vector_type(8))) __bf16  bf16x8;
typedef __attribute__((ext_vector_type(4))) float   f32x4;

__device__ __forceinline__ short f2bf(float f) {
  unsigned u = __builtin_bit_cast(unsigned, f);
  u += 0x7fffu + ((u >> 16) & 1u);          // round-to-nearest-even
  return (short)(u >> 16);
}

// two f32 -> packed bf16 pair via hardware packed cvt (m240). memcpy because
// __hip_bfloat162 is not trivially copyable (bit_cast rejected, r13).
__device__ __forceinline__ unsigned cvt2bf(float a, float b) {
  __hip_bfloat162 r = __float22bfloat162_rn(make_float2(a, b));
  unsigned u;
  __builtin_memcpy(&u, &r, 4);
  return u;
}

__device__ __forceinline__ f32x4 mfma16(s16x8 a, s16x8 b, f32x4 c) {
  return __builtin_amdgcn_mfma_f32_16x16x32_bf16(
      __builtin_bit_cast(bf16x8, a), __builtin_bit_cast(bf16x8, b), c, 0, 0, 0);
}

__device__ __forceinline__ void glds16(const short* g, short* l) {
  __builtin_amdgcn_global_load_lds(
      (__attribute__((address_space(1))) const void*)g,
      (__attribute__((address_space(3))) void*)l, 16, 0, 0);
}

// ---------------- merged transpose + cast of the 3 weights ----------------
__global__ __launch_bounds__(256) void transpose_cast_all(
    const float* __restrict__ s0, short* __restrict__ d0,
    const float* __restrict__ s1, short* __restrict__ d1,
    const float* __restrict__ s2, short* __restrict__ d2) {
  __shared__ float t[32 * 33];
  int id = blockIdx.x;
  const float* src; short* dst; int R, C, bx, by;
  if (id < 288)      { src = s0; dst = d0; R = 768; C = 384;  bx = id % 12;           by = id / 12; }
  else if (id < 720) { int l = id - 288; src = s1; dst = d1; R = 384; C = 1152; bx = l % 36; by = l / 36; }
  else               { int l = id - 720; src = s2; dst = d2; R = 384; C = 768;  bx = l % 24; by = l / 24; }
  int tid = threadIdx.x;
  int c0 = bx * 32, r0 = by * 32;
  for (int rep = 0; rep < 4; ++rep) {
    int idx = rep * 256 + tid;
    int rr = idx >> 5, cc = idx & 31;
    t[rr * 33 + cc] = src[(size_t)(r0 + rr) * C + c0 + cc];
  }
  __syncthreads();
  for (int rep = 0; rep < 4; ++rep) {
    int idx = rep * 256 + tid;
    int cc = idx >> 5, rr = idx & 31;
    dst[(size_t)(c0 + cc) * R + r0 + rr] = f2bf(t[rr * 33 + cc]);
  }
}

// ---------------- m97-style bf16 GEMM, templated block-M ----------------
// MODE 0: bf16 out. MODE 1: f32 out. MODE 2: qkv scatter (q pre-scaled).
// AF32: A is f32; reg-stage (issue early, convert+ds_write after MFMA).
// BM: block M-extent (128 or 64). BM=64 doubles the grid for small-N GEMMs
// (GEMM1 was 384 blocks = 1.5/CU, 2x load-imbalanced; now 768 = 3/CU).
template <int MODE, bool AF32, int BM>
__global__ __launch_bounds__(256, 2) void gemm_bf16(
    const short* __restrict__ A, const float* __restrict__ Af,
    const short* __restrict__ Bt,
    const float* __restrict__ bias, void* __restrict__ out,
    short* __restrict__ q_p, short* __restrict__ k_p, short* __restrict__ vtok,
    int M, int N, int K) {
  constexpr int WM  = BM / 2;    // wave M-extent
  constexpr int MI  = WM / 16;   // M fragments per wave
  constexpr int AIT = BM / 32;   // A-stage iterations (256 thr x 16B)
  __shared__ short lds[2][(BM + 128) * 64];
  int tid = threadIdx.x;
  int lane = tid & 63, wid = tid >> 6;
  int l15 = lane & 15, g = lane >> 4;
  int nbn = N >> 7;
  int nwg = gridDim.x;
  int bid = blockIdx.x;
  int chunk = nwg >> 3;                       // all grids are %8 == 0
  int swz_bid = (bid & 7) * chunk + (bid >> 3);
  int bm = swz_bid / nbn, bn = swz_bid % nbn;
  int wr = wid >> 1, wc = wid & 1;

  const short* Ab = AF32 ? nullptr : (A + (size_t)(bm * BM) * K);
  const float* Afb = AF32 ? (Af + (size_t)(bm * BM) * K) : nullptr;
  const short* Bb = Bt + (size_t)(bn * 128) * K;

  f32x4 acc[MI][4];
#pragma unroll
  for (int i = 0; i < MI; ++i)
#pragma unroll
    for (int j = 0; j < 4; ++j) acc[i][j] = (f32x4){0.f, 0.f, 0.f, 0.f};

  f32x4 areg[AIT][2];                         // AF32: 8 floats per c-slot
  int nk = K >> 6;

  auto stageB = [&](int bufi, int kt) {
    const short* gb = Bb + kt * 64;
#pragma unroll
    for (int it = 0; it < 4; ++it) {
      int c = it * 256 + tid;
      int row = c >> 3, pc = c & 7;
      int lc = pc ^ (row & 7);                // pre-swizzled source (rule #21)
      glds16(gb + (size_t)row * K + lc * 8,
             &lds[bufi][BM * 64 + (it * 256 + wid * 64) * 8]);
    }
  };
  auto stageA_lds = [&](int bufi, int kt) {
    const short* ga = Ab + kt * 64;
#pragma unroll
    for (int it = 0; it < AIT; ++it) {
      int c = it * 256 + tid;
      int row = c >> 3, pc = c & 7;
      int lc = pc ^ (row & 7);
      glds16(ga + (size_t)row * K + lc * 8,
             &lds[bufi][(it * 256 + wid * 64) * 8]);
    }
  };
  auto stageA_issue = [&](int kt) {           // f32 global -> regs (no wait yet)
#pragma unroll
    for (int it = 0; it < AIT; ++it) {
      int c = it * 256 + tid;
      int row = c >> 3, pc = c & 7;
      int lc = pc ^ (row & 7);
      const float* src = Afb + (size_t)row * K + kt * 64 + lc * 8;
      areg[it][0] = *(const f32x4*)(src);
      areg[it][1] = *(const f32x4*)(src + 4);
    }
  };
  auto stageA_write = [&](int bufi) {         // regs -> bf16 -> LDS (same image)
#pragma unroll
    for (int it = 0; it < AIT; ++it) {
      int c = it * 256 + tid;
      s16x8 o;
#pragma unroll
      for (int q = 0; q < 4; ++q) {
        o[q]     = f2bf(areg[it][0][q]);
        o[q + 4] = f2bf(areg[it][1][q]);
      }
      *(s16x8*)(&lds[bufi][0] + (size_t)c * 8) = o;
    }
  };

  if (AF32) { stageA_issue(0); stageB(0, 0); stageA_write(0); }
  else      { stageA_lds(0, 0); stageB(0, 0); }
  __syncthreads();
  int buf = 0;
  for (int kt = 0; kt < nk; ++kt) {
    bool more = (kt + 1 < nk);
    if (more) {
      if (AF32) stageA_issue(kt + 1); else stageA_lds(buf ^ 1, kt + 1);
      stageB(buf ^ 1, kt + 1);
    }
    const short* la = &lds[buf][0];
    const short* lb = &lds[buf][BM * 64];
    s16x8 af[MI][2], bfv[4][2];
#pragma unroll
    for (int i = 0; i < MI; ++i)
#pragma unroll
      for (int kk = 0; kk < 2; ++kk) {
        int row = wr * WM + i * 16 + l15;
        int ch = (kk * 4 + g) ^ (l15 & 7);
        af[i][kk] = *(const s16x8*)(la + row * 64 + ch * 8);
      }
#pragma unroll
    for (int j = 0; j < 4; ++j)
#pragma unroll
      for (int kk = 0; kk < 2; ++kk) {
        int row = wc * 64 + j * 16 + l15;
        int ch = (kk * 4 + g) ^ (l15 & 7);
        bfv[j][kk] = *(const s16x8*)(lb + row * 64 + ch * 8);
      }
#pragma unroll
    for (int kk = 0; kk < 2; ++kk)
#pragma unroll
      for (int i = 0; i < MI; ++i)
#pragma unroll
        for (int j = 0; j < 4; ++j)
          acc[i][j] = mfma16(af[i][kk], bfv[j][kk], acc[i][j]);
    if (AF32 && more) stageA_write(buf ^ 1);  // HBM latency hidden under MFMA
    __syncthreads();
    buf ^= 1;
  }

#pragma unroll
  for (int j = 0; j < 4; ++j) {
    int col = bn * 128 + wc * 64 + j * 16 + l15;
    float bv = bias[col];
    int which = 0, rem = 0, h = 0, d = 0;
    if (MODE == 2) {
      which = col / 384;
      rem = col - which * 384;
      h = rem >> 5; d = rem & 31;
    }
#pragma unroll
    for (int i = 0; i < MI; ++i) {
      int row0 = bm * BM + wr * WM + i * 16 + g * 4;
#pragma unroll
      for (int r = 0; r < 4; ++r) {
        int row = row0 + r;
        float v = acc[i][j][r] + bv;
        if (MODE == 1) {
          ((float*)out)[(size_t)row * N + col] = v;
        } else if (MODE == 0) {
          ((short*)out)[(size_t)row * N + col] = f2bf(v);
        } else {
          // fold hd^-0.5 * log2(e) into q so attn scores are in log2 units
          if (which == 0) v *= (0.17677669529663687f * 1.4426950408889634f);
          short bf = f2bf(v);
          if (which == 2) {
            vtok[(size_t)row * 384 + rem] = bf;
          } else {
            int b = row >> 12, s = (row >> 10) & 3, key = row & 1023;
            size_t dst = ((size_t)((b * 12 + h) * 4 + s) << 15) + key * 32 + d;
            if (which) k_p[dst] = bf; else q_p[dst] = bf;
          }
        }
      }
    }
  }
}

// ---------------- V transpose: vtok [16384][384] -> vt[bhs][32][1024] ----------------
__global__ __launch_bounds__(256) void v_transpose(
    const short* __restrict__ vtok, short* __restrict__ vt) {
  __shared__ short t[256 * 33];
  int tid = threadIdx.x;
  int bid = blockIdx.x;                        // 192*4
  int kc = bid & 3, bhs = bid >> 2;
  int s = bhs & 3, h = (bhs >> 2) % 12, b = bhs / 48;
  int key = kc * 256 + tid;
  int tok = b * 4096 + s * 1024 + key;
  const short* src = vtok + (size_t)tok * 384 + h * 32;
#pragma unroll
  for (int c = 0; c < 4; ++c) {
    s16x8 v = *(const s16x8*)(src + c * 8);
#pragma unroll
    for (int j = 0; j < 8; ++j) t[tid * 33 + c * 8 + j] = v[j];
  }
  __syncthreads();
  int d = tid >> 3, kb = tid & 7;
  short* dst = vt + ((size_t)((b * 12 + h) * 4 + s)) * 32768 + (size_t)d * 1024 + kc * 256 + kb * 32;
#pragma unroll
  for (int cc = 0; cc < 4; ++cc) {
    s16x8 o;
#pragma unroll
    for (int j = 0; j < 8; ++j) o[j] = t[(kb * 32 + cc * 8 + j) * 33 + d];
    *(s16x8*)(dst + cc * 8) = o;
  }
}

// ---------------- flash attention: swapped QK^T, 2-wave blocks (r15, parked) ----
// 85.5 us; all pipes <=34%, occupancy pinned ~33% regardless of LDS/VGPR
// (r10/r15 evidence) -> structural latency plateau. Per-wave body validated.
__global__ __launch_bounds__(128, 2) void attn_kernel(
    const short* __restrict__ qp, const short* __restrict__ kp,
    const short* __restrict__ vt, short* __restrict__ ob) {
  __shared__ short plds[2][32 * 136];          // per-wave P[32][272B]
  int tid = threadIdx.x;
  int lane = tid & 63, w = tid >> 6;           // w in {0,1}
  int l15 = lane & 15, g = lane >> 4;
  int bid = blockIdx.x;
  int bhs = bid % 192, qt = bid / 192;         // qt in 0..15, 64 q-rows each
  int s = bhs & 3, h = (bhs >> 2) % 12, b = bhs / 48;

  const short* qb = qp + ((size_t)bhs << 15) + (qt * 64 + w * 32) * 32;
  const short* kb = kp + ((size_t)bhs << 15);
  const short* vb = vt + ((size_t)bhs << 15);

  s16x8 qf[2];
#pragma unroll
  for (int i = 0; i < 2; ++i)
    qf[i] = *(const s16x8*)(qb + (i * 16 + l15) * 32 + g * 8);

  f32x4 oacc[2][2];
#pragma unroll
  for (int i = 0; i < 2; ++i)
#pragma unroll
    for (int n = 0; n < 2; ++n) oacc[i][n] = (f32x4){0.f, 0.f, 0.f, 0.f};
  float lsum[2] = {0.f, 0.f};

  char* pw = (char*)&plds[w][0];
  int swz = (l15 >> 3) << 4;                   // 1-bit XOR (row-pure, bijective)

  for (int t = 0; t < 8; ++t) {
    f32x4 sa[2][8];
#pragma unroll
    for (int i = 0; i < 2; ++i)
#pragma unroll
      for (int kn = 0; kn < 8; ++kn) sa[i][kn] = (f32x4){0.f, 0.f, 0.f, 0.f};
    __builtin_amdgcn_s_setprio(1);
#pragma unroll
    for (int kn = 0; kn < 8; ++kn) {
      s16x8 kf = *(const s16x8*)(kb + (size_t)(t * 128 + kn * 16 + l15) * 32 + g * 8);
      sa[0][kn] = mfma16(kf, qf[0], sa[0][kn]);
      sa[1][kn] = mfma16(kf, qf[1], sa[1][kn]);
    }
    __builtin_amdgcn_s_setprio(0);
    // numerators: p = exp2(sa) directly (q pre-scaled; shift cancels in ratio)
#pragma unroll
    for (int i = 0; i < 2; ++i) {
      float ps = 0.f;
#pragma unroll
      for (int kn = 0; kn < 8; ++kn) {
        float p0 = __builtin_amdgcn_exp2f(sa[i][kn][0]);
        float p1 = __builtin_amdgcn_exp2f(sa[i][kn][1]);
        float p2 = __builtin_amdgcn_exp2f(sa[i][kn][2]);
        float p3 = __builtin_amdgcn_exp2f(sa[i][kn][3]);
        ps += (p0 + p1) + (p2 + p3);
        uint2 u;
        u.x = cvt2bf(p0, p1);
        u.y = cvt2bf(p2, p3);
        *(s16x4*)(pw + (i * 16 + l15) * 272 + ((kn * 32 + g * 8) ^ swz)) =
            __builtin_bit_cast(s16x4, u);
      }
      lsum[i] += ps;                           // per-lane partial; reduced at end
    }
    // DS-only fence: P-stores stay before PV P-loads; VALU/VMEM/MFMA may cross
    __builtin_amdgcn_sched_barrier(0x7F);
    __builtin_amdgcn_s_setprio(1);
#pragma unroll
    for (int kk = 0; kk < 4; ++kk) {
      s16x8 pa[2];
#pragma unroll
      for (int i = 0; i < 2; ++i)
        pa[i] = *(const s16x8*)(pw + (i * 16 + l15) * 272 + ((kk * 64 + g * 16) ^ swz));
#pragma unroll
      for (int n = 0; n < 2; ++n) {
        s16x8 vf = *(const s16x8*)(vb + (size_t)(n * 16 + l15) * 1024 + t * 128 + kk * 32 + g * 8);
        oacc[0][n] = mfma16(vf, pa[0], oacc[0][n]);
        oacc[1][n] = mfma16(vf, pa[1], oacc[1][n]);
      }
    }
    __builtin_amdgcn_s_setprio(0);
    // DS-only fence: next tile's P-stores stay after this tile's P-loads
    __builtin_amdgcn_sched_barrier(0x7F);
  }
  // final denominator: sum across the 4 g-groups (keys partition over g)
#pragma unroll
  for (int i = 0; i < 2; ++i) {
    float v = lsum[i];
    v += __shfl_xor(v, 16);
    v += __shfl_xor(v, 32);
    lsum[i] = v;
  }
  int tokq0 = b * 4096 + s * 1024 + qt * 64 + w * 32;
#pragma unroll
  for (int i = 0; i < 2; ++i) {
    float inv = 1.0f / lsum[i];
    int tok = tokq0 + i * 16 + l15;
#pragma unroll
    for (int n = 0; n < 2; ++n) {
      uint2 u;
      u.x = cvt2bf(oacc[i][n][0] * inv, oacc[i][n][1] * inv);
      u.y = cvt2bf(oacc[i][n][2] * inv, oacc[i][n][3] * inv);
      *(s16x4*)(ob + (size_t)tok * 384 + h * 32 + n * 16 + g * 4) =
          __builtin_bit_cast(s16x4, u);
    }
  }
}

// ---------------- launch ----------------
extern "C" void kernel_launch(void* const* d_in, const int* in_sizes, int n_in,
                              void* d_out, int out_size, void* d_ws, size_t ws_size,
                              hipStream_t stream) {
  const float* x        = (const float*)d_in[0];   // [4,4096,768]
  const float* W_reduce = (const float*)d_in[1];   // [768,384]
  const float* b_reduce = (const float*)d_in[2];   // [384]
  const float* W_qkv    = (const float*)d_in[3];   // [384,1152]
  const float* b_qkv    = (const float*)d_in[4];   // [1152]
  const float* W_proj   = (const float*)d_in[5];   // [384,768]
  const float* b_proj   = (const float*)d_in[6];   // [768]
  float* out = (float*)d_out;                      // [16384,768]

  char* ws = (char*)d_ws;
  short* wr_t    = (short*)(ws + 0);               // [384][768]    589824 B
  short* wqkv_t  = (short*)(ws + 589824);          // [1152][384]   884736 B
  short* wproj_t = (short*)(ws + 1474560);         // [768][384]    589824 B
  short* xr_b    = (short*)(ws + 2064384);         // [16384][384]  12582912 B
  short* o_b     = xr_b;                           // reuse after qkv GEMM
  short* q_p     = (short*)(ws + 14647296);        // [192][1024][32] 12582912 B
  short* k_p     = (short*)(ws + 27230208);        // 12582912 B
  short* vtok    = (short*)(ws + 39813120);        // [16384][384]  12582912 B
  short* vt      = (short*)(ws + 52396032);        // [192][32][1024] 12582912 B; ends 64978944

  // all three weight transposes in one dispatch
  transpose_cast_all<<<1008, 256, 0, stream>>>(W_reduce, wr_t, W_qkv, wqkv_t, W_proj, wproj_t);

  // xr = x @ W_reduce + b_reduce  (f32 A fused-cast, bf16 out) — BM=64: 768 blocks
  gemm_bf16<0, true, 64><<<768, 256, 0, stream>>>(nullptr, x, wr_t, b_reduce, xr_b,
                                                  nullptr, nullptr, nullptr, 16384, 384, 768);
  // qkv = xr @ W_qkv + b_qkv  -> scatter to q_p / k_p / vtok (q pre-scaled) — BM=128
  gemm_bf16<2, false, 128><<<1152, 256, 0, stream>>>(xr_b, nullptr, wqkv_t, b_qkv, nullptr,
                                                     q_p, k_p, vtok, 16384, 1152, 384);
  // v transpose for PV fragments
  v_transpose<<<768, 256, 0, stream>>>(vtok, vt);
  // attention -> o_b  (2-wave blocks, 16 q-tiles per bhs)
  attn_kernel<<<3072, 128, 0, stream>>>(q_p, k_p, vt, o_b);
  // out = o @ W_proj + b_proj (f32 out) — BM=64: 1536 blocks
  gemm_bf16<1, false, 64><<<1536, 256, 0, stream>>>(o_b, nullptr, wproj_t, b_proj, (void*)out,
                                                    nullptr, nullptr, nullptr, 16384, 768, 384);
}

// Round 17
// 148.429 us; speedup vs baseline: 3.2311x; 1.0774x over previous
//
#include <hip/hip_runtime.h>
#include <hip/hip_bf16.h>

typedef __attribute__((ext_vector_type(8))) short   s16x8;
typedef __attribute__((ext_vector_type(4))) short   s16x4;
typedef __attribute__((ext_vector_type(8))) __bf16  bf16x8;
typedef __attribute__((ext_vector_type(4))) float   f32x4;

__device__ __forceinline__ short f2bf(float f) {
  unsigned u = __builtin_bit_cast(unsigned, f);
  u += 0x7fffu + ((u >> 16) & 1u);          // round-to-nearest-even
  return (short)(u >> 16);
}

// two f32 -> packed bf16 pair via hardware packed cvt (m240). memcpy because
// __hip_bfloat162 is not trivially copyable (bit_cast rejected, r13).
__device__ __forceinline__ unsigned cvt2bf(float a, float b) {
  __hip_bfloat162 r = __float22bfloat162_rn(make_float2(a, b));
  unsigned u;
  __builtin_memcpy(&u, &r, 4);
  return u;
}

__device__ __forceinline__ f32x4 mfma16(s16x8 a, s16x8 b, f32x4 c) {
  return __builtin_amdgcn_mfma_f32_16x16x32_bf16(
      __builtin_bit_cast(bf16x8, a), __builtin_bit_cast(bf16x8, b), c, 0, 0, 0);
}

__device__ __forceinline__ void glds16(const short* g, short* l) {
  __builtin_amdgcn_global_load_lds(
      (__attribute__((address_space(1))) const void*)g,
      (__attribute__((address_space(3))) void*)l, 16, 0, 0);
}

// ---------------- merged transpose + cast of the 3 weights ----------------
__global__ __launch_bounds__(256) void transpose_cast_all(
    const float* __restrict__ s0, short* __restrict__ d0,
    const float* __restrict__ s1, short* __restrict__ d1,
    const float* __restrict__ s2, short* __restrict__ d2) {
  __shared__ float t[32 * 33];
  int id = blockIdx.x;
  const float* src; short* dst; int R, C, bx, by;
  if (id < 288)      { src = s0; dst = d0; R = 768; C = 384;  bx = id % 12;           by = id / 12; }
  else if (id < 720) { int l = id - 288; src = s1; dst = d1; R = 384; C = 1152; bx = l % 36; by = l / 36; }
  else               { int l = id - 720; src = s2; dst = d2; R = 384; C = 768;  bx = l % 24; by = l / 24; }
  int tid = threadIdx.x;
  int c0 = bx * 32, r0 = by * 32;
  for (int rep = 0; rep < 4; ++rep) {
    int idx = rep * 256 + tid;
    int rr = idx >> 5, cc = idx & 31;
    t[rr * 33 + cc] = src[(size_t)(r0 + rr) * C + c0 + cc];
  }
  __syncthreads();
  for (int rep = 0; rep < 4; ++rep) {
    int idx = rep * 256 + tid;
    int cc = idx >> 5, rr = idx & 31;
    dst[(size_t)(c0 + cc) * R + r0 + rr] = f2bf(t[rr * 33 + cc]);
  }
}

// ---------------- m97-style bf16 GEMM, templated block-M ----------------
// MODE 0: bf16 out. MODE 1: f32 out. MODE 2: qkv scatter (q pre-scaled),
//   V written DIRECTLY to vt[bhs][d][1024] (transposed) as s16x4 quads —
//   the r16 v_transpose dispatch + vtok round-trip are deleted.
// AF32: A is f32; reg-stage (issue early, convert+ds_write after MFMA).
// BM: block M-extent (128 or 64).
template <int MODE, bool AF32, int BM>
__global__ __launch_bounds__(256, 2) void gemm_bf16(
    const short* __restrict__ A, const float* __restrict__ Af,
    const short* __restrict__ Bt,
    const float* __restrict__ bias, void* __restrict__ out,
    short* __restrict__ q_p, short* __restrict__ k_p, short* __restrict__ vt,
    int M, int N, int K) {
  constexpr int WM  = BM / 2;    // wave M-extent
  constexpr int MI  = WM / 16;   // M fragments per wave
  constexpr int AIT = BM / 32;   // A-stage iterations (256 thr x 16B)
  __shared__ short lds[2][(BM + 128) * 64];
  int tid = threadIdx.x;
  int lane = tid & 63, wid = tid >> 6;
  int l15 = lane & 15, g = lane >> 4;
  int nbn = N >> 7;
  int nwg = gridDim.x;
  int bid = blockIdx.x;
  int chunk = nwg >> 3;                       // all grids are %8 == 0
  int swz_bid = (bid & 7) * chunk + (bid >> 3);
  int bm = swz_bid / nbn, bn = swz_bid % nbn;
  int wr = wid >> 1, wc = wid & 1;

  const short* Ab = AF32 ? nullptr : (A + (size_t)(bm * BM) * K);
  const float* Afb = AF32 ? (Af + (size_t)(bm * BM) * K) : nullptr;
  const short* Bb = Bt + (size_t)(bn * 128) * K;

  f32x4 acc[MI][4];
#pragma unroll
  for (int i = 0; i < MI; ++i)
#pragma unroll
    for (int j = 0; j < 4; ++j) acc[i][j] = (f32x4){0.f, 0.f, 0.f, 0.f};

  f32x4 areg[AIT][2];                         // AF32: 8 floats per c-slot
  int nk = K >> 6;

  auto stageB = [&](int bufi, int kt) {
    const short* gb = Bb + kt * 64;
#pragma unroll
    for (int it = 0; it < 4; ++it) {
      int c = it * 256 + tid;
      int row = c >> 3, pc = c & 7;
      int lc = pc ^ (row & 7);                // pre-swizzled source (rule #21)
      glds16(gb + (size_t)row * K + lc * 8,
             &lds[bufi][BM * 64 + (it * 256 + wid * 64) * 8]);
    }
  };
  auto stageA_lds = [&](int bufi, int kt) {
    const short* ga = Ab + kt * 64;
#pragma unroll
    for (int it = 0; it < AIT; ++it) {
      int c = it * 256 + tid;
      int row = c >> 3, pc = c & 7;
      int lc = pc ^ (row & 7);
      glds16(ga + (size_t)row * K + lc * 8,
             &lds[bufi][(it * 256 + wid * 64) * 8]);
    }
  };
  auto stageA_issue = [&](int kt) {           // f32 global -> regs (no wait yet)
#pragma unroll
    for (int it = 0; it < AIT; ++it) {
      int c = it * 256 + tid;
      int row = c >> 3, pc = c & 7;
      int lc = pc ^ (row & 7);
      const float* src = Afb + (size_t)row * K + kt * 64 + lc * 8;
      areg[it][0] = *(const f32x4*)(src);
      areg[it][1] = *(const f32x4*)(src + 4);
    }
  };
  auto stageA_write = [&](int bufi) {         // regs -> bf16 -> LDS (same image)
#pragma unroll
    for (int it = 0; it < AIT; ++it) {
      int c = it * 256 + tid;
      s16x8 o;
#pragma unroll
      for (int q = 0; q < 4; ++q) {
        o[q]     = f2bf(areg[it][0][q]);
        o[q + 4] = f2bf(areg[it][1][q]);
      }
      *(s16x8*)(&lds[bufi][0] + (size_t)c * 8) = o;
    }
  };

  if (AF32) { stageA_issue(0); stageB(0, 0); stageA_write(0); }
  else      { stageA_lds(0, 0); stageB(0, 0); }
  __syncthreads();
  int buf = 0;
  for (int kt = 0; kt < nk; ++kt) {
    bool more = (kt + 1 < nk);
    if (more) {
      if (AF32) stageA_issue(kt + 1); else stageA_lds(buf ^ 1, kt + 1);
      stageB(buf ^ 1, kt + 1);
    }
    const short* la = &lds[buf][0];
    const short* lb = &lds[buf][BM * 64];
    s16x8 af[MI][2], bfv[4][2];
#pragma unroll
    for (int i = 0; i < MI; ++i)
#pragma unroll
      for (int kk = 0; kk < 2; ++kk) {
        int row = wr * WM + i * 16 + l15;
        int ch = (kk * 4 + g) ^ (l15 & 7);
        af[i][kk] = *(const s16x8*)(la + row * 64 + ch * 8);
      }
#pragma unroll
    for (int j = 0; j < 4; ++j)
#pragma unroll
      for (int kk = 0; kk < 2; ++kk) {
        int row = wc * 64 + j * 16 + l15;
        int ch = (kk * 4 + g) ^ (l15 & 7);
        bfv[j][kk] = *(const s16x8*)(lb + row * 64 + ch * 8);
      }
#pragma unroll
    for (int kk = 0; kk < 2; ++kk)
#pragma unroll
      for (int i = 0; i < MI; ++i)
#pragma unroll
        for (int j = 0; j < 4; ++j)
          acc[i][j] = mfma16(af[i][kk], bfv[j][kk], acc[i][j]);
    if (AF32 && more) stageA_write(buf ^ 1);  // HBM latency hidden under MFMA
    __syncthreads();
    buf ^= 1;
  }

#pragma unroll
  for (int j = 0; j < 4; ++j) {
    int col = bn * 128 + wc * 64 + j * 16 + l15;
    float bv = bias[col];
    int which = 0, rem = 0, h = 0, d = 0;
    if (MODE == 2) {
      which = col / 384;
      rem = col - which * 384;
      h = rem >> 5; d = rem & 31;
    }
#pragma unroll
    for (int i = 0; i < MI; ++i) {
      int row0 = bm * BM + wr * WM + i * 16 + g * 4;
      if (MODE == 2 && which == 2) {
        // V: write vt[bhs][d][key] directly; 4 consecutive keys = one s16x4
        int b = row0 >> 12, s = (row0 >> 10) & 3, key = row0 & 1023;
        s16x4 o;
#pragma unroll
        for (int r = 0; r < 4; ++r) o[r] = f2bf(acc[i][j][r] + bv);
        *(s16x4*)(vt + ((size_t)((b * 12 + h) * 4 + s) << 15) + d * 1024 + key) = o;
        continue;
      }
#pragma unroll
      for (int r = 0; r < 4; ++r) {
        int row = row0 + r;
        float v = acc[i][j][r] + bv;
        if (MODE == 1) {
          ((float*)out)[(size_t)row * N + col] = v;
        } else if (MODE == 0) {
          ((short*)out)[(size_t)row * N + col] = f2bf(v);
        } else {
          // fold hd^-0.5 * log2(e) into q so attn scores are in log2 units
          if (which == 0) v *= (0.17677669529663687f * 1.4426950408889634f);
          short bf = f2bf(v);
          int b = row >> 12, s = (row >> 10) & 3, key = row & 1023;
          size_t dst = ((size_t)((b * 12 + h) * 4 + s) << 15) + key * 32 + d;
          if (which) k_p[dst] = bf; else q_p[dst] = bf;
        }
      }
    }
  }
}

// ---------------- flash attention: swapped QK^T, 2-wave blocks (r15, parked) ----
// 85.5 us; all pipes <=34%, occupancy pinned ~33% regardless of LDS/VGPR
// (r10/r15 evidence) -> structural latency plateau. Per-wave body validated.
__global__ __launch_bounds__(128, 2) void attn_kernel(
    const short* __restrict__ qp, const short* __restrict__ kp,
    const short* __restrict__ vt, short* __restrict__ ob) {
  __shared__ short plds[2][32 * 136];          // per-wave P[32][272B]
  int tid = threadIdx.x;
  int lane = tid & 63, w = tid >> 6;           // w in {0,1}
  int l15 = lane & 15, g = lane >> 4;
  int bid = blockIdx.x;
  int bhs = bid % 192, qt = bid / 192;         // qt in 0..15, 64 q-rows each
  int s = bhs & 3, h = (bhs >> 2) % 12, b = bhs / 48;

  const short* qb = qp + ((size_t)bhs << 15) + (qt * 64 + w * 32) * 32;
  const short* kb = kp + ((size_t)bhs << 15);
  const short* vb = vt + ((size_t)bhs << 15);

  s16x8 qf[2];
#pragma unroll
  for (int i = 0; i < 2; ++i)
    qf[i] = *(const s16x8*)(qb + (i * 16 + l15) * 32 + g * 8);

  f32x4 oacc[2][2];
#pragma unroll
  for (int i = 0; i < 2; ++i)
#pragma unroll
    for (int n = 0; n < 2; ++n) oacc[i][n] = (f32x4){0.f, 0.f, 0.f, 0.f};
  float lsum[2] = {0.f, 0.f};

  char* pw = (char*)&plds[w][0];
  int swz = (l15 >> 3) << 4;                   // 1-bit XOR (row-pure, bijective)

  for (int t = 0; t < 8; ++t) {
    f32x4 sa[2][8];
#pragma unroll
    for (int i = 0; i < 2; ++i)
#pragma unroll
      for (int kn = 0; kn < 8; ++kn) sa[i][kn] = (f32x4){0.f, 0.f, 0.f, 0.f};
    __builtin_amdgcn_s_setprio(1);
#pragma unroll
    for (int kn = 0; kn < 8; ++kn) {
      s16x8 kf = *(const s16x8*)(kb + (size_t)(t * 128 + kn * 16 + l15) * 32 + g * 8);
      sa[0][kn] = mfma16(kf, qf[0], sa[0][kn]);
      sa[1][kn] = mfma16(kf, qf[1], sa[1][kn]);
    }
    __builtin_amdgcn_s_setprio(0);
    // numerators: p = exp2(sa) directly (q pre-scaled; shift cancels in ratio)
#pragma unroll
    for (int i = 0; i < 2; ++i) {
      float ps = 0.f;
#pragma unroll
      for (int kn = 0; kn < 8; ++kn) {
        float p0 = __builtin_amdgcn_exp2f(sa[i][kn][0]);
        float p1 = __builtin_amdgcn_exp2f(sa[i][kn][1]);
        float p2 = __builtin_amdgcn_exp2f(sa[i][kn][2]);
        float p3 = __builtin_amdgcn_exp2f(sa[i][kn][3]);
        ps += (p0 + p1) + (p2 + p3);
        uint2 u;
        u.x = cvt2bf(p0, p1);
        u.y = cvt2bf(p2, p3);
        *(s16x4*)(pw + (i * 16 + l15) * 272 + ((kn * 32 + g * 8) ^ swz)) =
            __builtin_bit_cast(s16x4, u);
      }
      lsum[i] += ps;                           // per-lane partial; reduced at end
    }
    // DS-only fence: P-stores stay before PV P-loads; VALU/VMEM/MFMA may cross
    __builtin_amdgcn_sched_barrier(0x7F);
    __builtin_amdgcn_s_setprio(1);
#pragma unroll
    for (int kk = 0; kk < 4; ++kk) {
      s16x8 pa[2];
#pragma unroll
      for (int i = 0; i < 2; ++i)
        pa[i] = *(const s16x8*)(pw + (i * 16 + l15) * 272 + ((kk * 64 + g * 16) ^ swz));
#pragma unroll
      for (int n = 0; n < 2; ++n) {
        s16x8 vf = *(const s16x8*)(vb + (size_t)(n * 16 + l15) * 1024 + t * 128 + kk * 32 + g * 8);
        oacc[0][n] = mfma16(vf, pa[0], oacc[0][n]);
        oacc[1][n] = mfma16(vf, pa[1], oacc[1][n]);
      }
    }
    __builtin_amdgcn_s_setprio(0);
    // DS-only fence: next tile's P-stores stay after this tile's P-loads
    __builtin_amdgcn_sched_barrier(0x7F);
  }
  // final denominator: sum across the 4 g-groups (keys partition over g)
#pragma unroll
  for (int i = 0; i < 2; ++i) {
    float v = lsum[i];
    v += __shfl_xor(v, 16);
    v += __shfl_xor(v, 32);
    lsum[i] = v;
  }
  int tokq0 = b * 4096 + s * 1024 + qt * 64 + w * 32;
#pragma unroll
  for (int i = 0; i < 2; ++i) {
    float inv = 1.0f / lsum[i];
    int tok = tokq0 + i * 16 + l15;
#pragma unroll
    for (int n = 0; n < 2; ++n) {
      uint2 u;
      u.x = cvt2bf(oacc[i][n][0] * inv, oacc[i][n][1] * inv);
      u.y = cvt2bf(oacc[i][n][2] * inv, oacc[i][n][3] * inv);
      *(s16x4*)(ob + (size_t)tok * 384 + h * 32 + n * 16 + g * 4) =
          __builtin_bit_cast(s16x4, u);
    }
  }
}

// ---------------- launch ----------------
extern "C" void kernel_launch(void* const* d_in, const int* in_sizes, int n_in,
                              void* d_out, int out_size, void* d_ws, size_t ws_size,
                              hipStream_t stream) {
  const float* x        = (const float*)d_in[0];   // [4,4096,768]
  const float* W_reduce = (const float*)d_in[1];   // [768,384]
  const float* b_reduce = (const float*)d_in[2];   // [384]
  const float* W_qkv    = (const float*)d_in[3];   // [384,1152]
  const float* b_qkv    = (const float*)d_in[4];   // [1152]
  const float* W_proj   = (const float*)d_in[5];   // [384,768]
  const float* b_proj   = (const float*)d_in[6];   // [768]
  float* out = (float*)d_out;                      // [16384,768]

  char* ws = (char*)d_ws;
  short* wr_t    = (short*)(ws + 0);               // [384][768]    589824 B
  short* wqkv_t  = (short*)(ws + 589824);          // [1152][384]   884736 B
  short* wproj_t = (short*)(ws + 1474560);         // [768][384]    589824 B
  short* xr_b    = (short*)(ws + 2064384);         // [16384][384]  12582912 B
  short* o_b     = xr_b;                           // reuse after qkv GEMM
  short* q_p     = (short*)(ws + 14647296);        // [192][1024][32] 12582912 B
  short* k_p     = (short*)(ws + 27230208);        // 12582912 B
  short* vt      = (short*)(ws + 39813120);        // [192][32][1024] 12582912 B
                                                   // (vtok slot freed; ends 52396032)

  // all three weight transposes in one dispatch
  transpose_cast_all<<<1008, 256, 0, stream>>>(W_reduce, wr_t, W_qkv, wqkv_t, W_proj, wproj_t);

  // xr = x @ W_reduce + b_reduce  (f32 A fused-cast, bf16 out) — BM=64: 768 blocks
  gemm_bf16<0, true, 64><<<768, 256, 0, stream>>>(nullptr, x, wr_t, b_reduce, xr_b,
                                                  nullptr, nullptr, nullptr, 16384, 384, 768);
  // qkv = xr @ W_qkv + b_qkv  -> scatter q_p / k_p / vt-direct (q pre-scaled)
  gemm_bf16<2, false, 128><<<1152, 256, 0, stream>>>(xr_b, nullptr, wqkv_t, b_qkv, nullptr,
                                                     q_p, k_p, vt, 16384, 1152, 384);
  // attention -> o_b  (2-wave blocks, 16 q-tiles per bhs)
  attn_kernel<<<3072, 128, 0, stream>>>(q_p, k_p, vt, o_b);
  // out = o @ W_proj + b_proj (f32 out) — BM=64: 1536 blocks
  gemm_bf16<1, false, 64><<<1536, 256, 0, stream>>>(o_b, nullptr, wproj_t, b_proj, (void*)out,
                                                    nullptr, nullptr, nullptr, 16384, 768, 384);
}

// Round 18
// 138.078 us; speedup vs baseline: 3.4733x; 1.0750x over previous
//
#include <hip/hip_runtime.h>
#include <hip/hip_bf16.h>

typedef __attribute__((ext_vector_type(8))) short   s16x8;
typedef __attribute__((ext_vector_type(4))) short   s16x4;
typedef __attribute__((ext_vector_type(8))) __bf16  bf16x8;
typedef __attribute__((ext_vector_type(4))) float   f32x4;

__device__ __forceinline__ short f2bf(float f) {
  unsigned u = __builtin_bit_cast(unsigned, f);
  u += 0x7fffu + ((u >> 16) & 1u);          // round-to-nearest-even
  return (short)(u >> 16);
}

// two f32 -> packed bf16 pair via hardware packed cvt (m240). memcpy because
// __hip_bfloat162 is not trivially copyable (bit_cast rejected, r13).
__device__ __forceinline__ unsigned cvt2bf(float a, float b) {
  __hip_bfloat162 r = __float22bfloat162_rn(make_float2(a, b));
  unsigned u;
  __builtin_memcpy(&u, &r, 4);
  return u;
}

__device__ __forceinline__ f32x4 mfma16(s16x8 a, s16x8 b, f32x4 c) {
  return __builtin_amdgcn_mfma_f32_16x16x32_bf16(
      __builtin_bit_cast(bf16x8, a), __builtin_bit_cast(bf16x8, b), c, 0, 0, 0);
}

__device__ __forceinline__ void glds16(const short* g, short* l) {
  __builtin_amdgcn_global_load_lds(
      (__attribute__((address_space(1))) const void*)g,
      (__attribute__((address_space(3))) void*)l, 16, 0, 0);
}

// ---------------- merged transpose + cast of the 3 weights ----------------
__global__ __launch_bounds__(256) void transpose_cast_all(
    const float* __restrict__ s0, short* __restrict__ d0,
    const float* __restrict__ s1, short* __restrict__ d1,
    const float* __restrict__ s2, short* __restrict__ d2) {
  __shared__ float t[32 * 33];
  int id = blockIdx.x;
  const float* src; short* dst; int R, C, bx, by;
  if (id < 288)      { src = s0; dst = d0; R = 768; C = 384;  bx = id % 12;           by = id / 12; }
  else if (id < 720) { int l = id - 288; src = s1; dst = d1; R = 384; C = 1152; bx = l % 36; by = l / 36; }
  else               { int l = id - 720; src = s2; dst = d2; R = 384; C = 768;  bx = l % 24; by = l / 24; }
  int tid = threadIdx.x;
  int c0 = bx * 32, r0 = by * 32;
  for (int rep = 0; rep < 4; ++rep) {
    int idx = rep * 256 + tid;
    int rr = idx >> 5, cc = idx & 31;
    t[rr * 33 + cc] = src[(size_t)(r0 + rr) * C + c0 + cc];
  }
  __syncthreads();
  for (int rep = 0; rep < 4; ++rep) {
    int idx = rep * 256 + tid;
    int cc = idx >> 5, rr = idx & 31;
    dst[(size_t)(c0 + cc) * R + r0 + rr] = f2bf(t[rr * 33 + cc]);
  }
}

// ---------------- m97-style bf16 GEMM, templated block-M ----------------
// MODE 0: bf16 out. MODE 1: f32 out. MODE 2: qkv scatter (q pre-scaled),
//   V written DIRECTLY to vt[bhs][d][1024] (transposed) as s16x4 quads.
// AF32: A is f32; reg-stage (issue early, convert+ds_write after MFMA).
// BM: block M-extent (128 or 64). BM=64 everywhere: finer grid granularity
// (r16/r18: tail-round idle shrinks; GEMM2 2.25->4.5 rounds = ~17% less waste).
template <int MODE, bool AF32, int BM>
__global__ __launch_bounds__(256, 2) void gemm_bf16(
    const short* __restrict__ A, const float* __restrict__ Af,
    const short* __restrict__ Bt,
    const float* __restrict__ bias, void* __restrict__ out,
    short* __restrict__ q_p, short* __restrict__ k_p, short* __restrict__ vt,
    int M, int N, int K) {
  constexpr int WM  = BM / 2;    // wave M-extent
  constexpr int MI  = WM / 16;   // M fragments per wave
  constexpr int AIT = BM / 32;   // A-stage iterations (256 thr x 16B)
  __shared__ short lds[2][(BM + 128) * 64];
  int tid = threadIdx.x;
  int lane = tid & 63, wid = tid >> 6;
  int l15 = lane & 15, g = lane >> 4;
  int nbn = N >> 7;
  int nwg = gridDim.x;
  int bid = blockIdx.x;
  int chunk = nwg >> 3;                       // all grids are %8 == 0
  int swz_bid = (bid & 7) * chunk + (bid >> 3);
  int bm = swz_bid / nbn, bn = swz_bid % nbn;
  int wr = wid >> 1, wc = wid & 1;

  const short* Ab = AF32 ? nullptr : (A + (size_t)(bm * BM) * K);
  const float* Afb = AF32 ? (Af + (size_t)(bm * BM) * K) : nullptr;
  const short* Bb = Bt + (size_t)(bn * 128) * K;

  f32x4 acc[MI][4];
#pragma unroll
  for (int i = 0; i < MI; ++i)
#pragma unroll
    for (int j = 0; j < 4; ++j) acc[i][j] = (f32x4){0.f, 0.f, 0.f, 0.f};

  f32x4 areg[AIT][2];                         // AF32: 8 floats per c-slot
  int nk = K >> 6;

  auto stageB = [&](int bufi, int kt) {
    const short* gb = Bb + kt * 64;
#pragma unroll
    for (int it = 0; it < 4; ++it) {
      int c = it * 256 + tid;
      int row = c >> 3, pc = c & 7;
      int lc = pc ^ (row & 7);                // pre-swizzled source (rule #21)
      glds16(gb + (size_t)row * K + lc * 8,
             &lds[bufi][BM * 64 + (it * 256 + wid * 64) * 8]);
    }
  };
  auto stageA_lds = [&](int bufi, int kt) {
    const short* ga = Ab + kt * 64;
#pragma unroll
    for (int it = 0; it < AIT; ++it) {
      int c = it * 256 + tid;
      int row = c >> 3, pc = c & 7;
      int lc = pc ^ (row & 7);
      glds16(ga + (size_t)row * K + lc * 8,
             &lds[bufi][(it * 256 + wid * 64) * 8]);
    }
  };
  auto stageA_issue = [&](int kt) {           // f32 global -> regs (no wait yet)
#pragma unroll
    for (int it = 0; it < AIT; ++it) {
      int c = it * 256 + tid;
      int row = c >> 3, pc = c & 7;
      int lc = pc ^ (row & 7);
      const float* src = Afb + (size_t)row * K + kt * 64 + lc * 8;
      areg[it][0] = *(const f32x4*)(src);
      areg[it][1] = *(const f32x4*)(src + 4);
    }
  };
  auto stageA_write = [&](int bufi) {         // regs -> bf16 -> LDS (same image)
#pragma unroll
    for (int it = 0; it < AIT; ++it) {
      int c = it * 256 + tid;
      s16x8 o;
#pragma unroll
      for (int q = 0; q < 4; ++q) {
        o[q]     = f2bf(areg[it][0][q]);
        o[q + 4] = f2bf(areg[it][1][q]);
      }
      *(s16x8*)(&lds[bufi][0] + (size_t)c * 8) = o;
    }
  };

  if (AF32) { stageA_issue(0); stageB(0, 0); stageA_write(0); }
  else      { stageA_lds(0, 0); stageB(0, 0); }
  __syncthreads();
  int buf = 0;
  for (int kt = 0; kt < nk; ++kt) {
    bool more = (kt + 1 < nk);
    if (more) {
      if (AF32) stageA_issue(kt + 1); else stageA_lds(buf ^ 1, kt + 1);
      stageB(buf ^ 1, kt + 1);
    }
    const short* la = &lds[buf][0];
    const short* lb = &lds[buf][BM * 64];
    s16x8 af[MI][2], bfv[4][2];
#pragma unroll
    for (int i = 0; i < MI; ++i)
#pragma unroll
      for (int kk = 0; kk < 2; ++kk) {
        int row = wr * WM + i * 16 + l15;
        int ch = (kk * 4 + g) ^ (l15 & 7);
        af[i][kk] = *(const s16x8*)(la + row * 64 + ch * 8);
      }
#pragma unroll
    for (int j = 0; j < 4; ++j)
#pragma unroll
      for (int kk = 0; kk < 2; ++kk) {
        int row = wc * 64 + j * 16 + l15;
        int ch = (kk * 4 + g) ^ (l15 & 7);
        bfv[j][kk] = *(const s16x8*)(lb + row * 64 + ch * 8);
      }
#pragma unroll
    for (int kk = 0; kk < 2; ++kk)
#pragma unroll
      for (int i = 0; i < MI; ++i)
#pragma unroll
        for (int j = 0; j < 4; ++j)
          acc[i][j] = mfma16(af[i][kk], bfv[j][kk], acc[i][j]);
    if (AF32 && more) stageA_write(buf ^ 1);  // HBM latency hidden under MFMA
    __syncthreads();
    buf ^= 1;
  }

#pragma unroll
  for (int j = 0; j < 4; ++j) {
    int col = bn * 128 + wc * 64 + j * 16 + l15;
    float bv = bias[col];
    int which = 0, rem = 0, h = 0, d = 0;
    if (MODE == 2) {
      which = col / 384;
      rem = col - which * 384;
      h = rem >> 5; d = rem & 31;
    }
#pragma unroll
    for (int i = 0; i < MI; ++i) {
      int row0 = bm * BM + wr * WM + i * 16 + g * 4;
      if (MODE == 2 && which == 2) {
        // V: write vt[bhs][d][key] directly; 4 consecutive keys = one s16x4
        int b = row0 >> 12, s = (row0 >> 10) & 3, key = row0 & 1023;
        s16x4 o;
#pragma unroll
        for (int r = 0; r < 4; ++r) o[r] = f2bf(acc[i][j][r] + bv);
        *(s16x4*)(vt + ((size_t)((b * 12 + h) * 4 + s) << 15) + d * 1024 + key) = o;
        continue;
      }
#pragma unroll
      for (int r = 0; r < 4; ++r) {
        int row = row0 + r;
        float v = acc[i][j][r] + bv;
        if (MODE == 1) {
          ((float*)out)[(size_t)row * N + col] = v;
        } else if (MODE == 0) {
          ((short*)out)[(size_t)row * N + col] = f2bf(v);
        } else {
          // fold hd^-0.5 * log2(e) into q so attn scores are in log2 units
          if (which == 0) v *= (0.17677669529663687f * 1.4426950408889634f);
          short bf = f2bf(v);
          int b = row >> 12, s = (row >> 10) & 3, key = row & 1023;
          size_t dst = ((size_t)((b * 12 + h) * 4 + s) << 15) + key * 32 + d;
          if (which) k_p[dst] = bf; else q_p[dst] = bf;
        }
      }
    }
  }
}

// ---------------- flash attention: swapped QK^T, 2-wave blocks ----------------
// r17 body with s_setprio REMOVED (never isolated; bundled into r5. m190:
// setprio hurts without wave phase-role diversity — our 2 waves run near-
// lockstep, no producer/consumer split). Everything else byte-identical.
__global__ __launch_bounds__(128, 2) void attn_kernel(
    const short* __restrict__ qp, const short* __restrict__ kp,
    const short* __restrict__ vt, short* __restrict__ ob) {
  __shared__ short plds[2][32 * 136];          // per-wave P[32][272B]
  int tid = threadIdx.x;
  int lane = tid & 63, w = tid >> 6;           // w in {0,1}
  int l15 = lane & 15, g = lane >> 4;
  int bid = blockIdx.x;
  int bhs = bid % 192, qt = bid / 192;         // qt in 0..15, 64 q-rows each
  int s = bhs & 3, h = (bhs >> 2) % 12, b = bhs / 48;

  const short* qb = qp + ((size_t)bhs << 15) + (qt * 64 + w * 32) * 32;
  const short* kb = kp + ((size_t)bhs << 15);
  const short* vb = vt + ((size_t)bhs << 15);

  s16x8 qf[2];
#pragma unroll
  for (int i = 0; i < 2; ++i)
    qf[i] = *(const s16x8*)(qb + (i * 16 + l15) * 32 + g * 8);

  f32x4 oacc[2][2];
#pragma unroll
  for (int i = 0; i < 2; ++i)
#pragma unroll
    for (int n = 0; n < 2; ++n) oacc[i][n] = (f32x4){0.f, 0.f, 0.f, 0.f};
  float lsum[2] = {0.f, 0.f};

  char* pw = (char*)&plds[w][0];
  int swz = (l15 >> 3) << 4;                   // 1-bit XOR (row-pure, bijective)

  for (int t = 0; t < 8; ++t) {
    f32x4 sa[2][8];
#pragma unroll
    for (int i = 0; i < 2; ++i)
#pragma unroll
      for (int kn = 0; kn < 8; ++kn) sa[i][kn] = (f32x4){0.f, 0.f, 0.f, 0.f};
#pragma unroll
    for (int kn = 0; kn < 8; ++kn) {
      s16x8 kf = *(const s16x8*)(kb + (size_t)(t * 128 + kn * 16 + l15) * 32 + g * 8);
      sa[0][kn] = mfma16(kf, qf[0], sa[0][kn]);
      sa[1][kn] = mfma16(kf, qf[1], sa[1][kn]);
    }
    // numerators: p = exp2(sa) directly (q pre-scaled; shift cancels in ratio)
#pragma unroll
    for (int i = 0; i < 2; ++i) {
      float ps = 0.f;
#pragma unroll
      for (int kn = 0; kn < 8; ++kn) {
        float p0 = __builtin_amdgcn_exp2f(sa[i][kn][0]);
        float p1 = __builtin_amdgcn_exp2f(sa[i][kn][1]);
        float p2 = __builtin_amdgcn_exp2f(sa[i][kn][2]);
        float p3 = __builtin_amdgcn_exp2f(sa[i][kn][3]);
        ps += (p0 + p1) + (p2 + p3);
        uint2 u;
        u.x = cvt2bf(p0, p1);
        u.y = cvt2bf(p2, p3);
        *(s16x4*)(pw + (i * 16 + l15) * 272 + ((kn * 32 + g * 8) ^ swz)) =
            __builtin_bit_cast(s16x4, u);
      }
      lsum[i] += ps;                           // per-lane partial; reduced at end
    }
    // DS-only fence: P-stores stay before PV P-loads; VALU/VMEM/MFMA may cross
    __builtin_amdgcn_sched_barrier(0x7F);
#pragma unroll
    for (int kk = 0; kk < 4; ++kk) {
      s16x8 pa[2];
#pragma unroll
      for (int i = 0; i < 2; ++i)
        pa[i] = *(const s16x8*)(pw + (i * 16 + l15) * 272 + ((kk * 64 + g * 16) ^ swz));
#pragma unroll
      for (int n = 0; n < 2; ++n) {
        s16x8 vf = *(const s16x8*)(vb + (size_t)(n * 16 + l15) * 1024 + t * 128 + kk * 32 + g * 8);
        oacc[0][n] = mfma16(vf, pa[0], oacc[0][n]);
        oacc[1][n] = mfma16(vf, pa[1], oacc[1][n]);
      }
    }
    // DS-only fence: next tile's P-stores stay after this tile's P-loads
    __builtin_amdgcn_sched_barrier(0x7F);
  }
  // final denominator: sum across the 4 g-groups (keys partition over g)
#pragma unroll
  for (int i = 0; i < 2; ++i) {
    float v = lsum[i];
    v += __shfl_xor(v, 16);
    v += __shfl_xor(v, 32);
    lsum[i] = v;
  }
  int tokq0 = b * 4096 + s * 1024 + qt * 64 + w * 32;
#pragma unroll
  for (int i = 0; i < 2; ++i) {
    float inv = 1.0f / lsum[i];
    int tok = tokq0 + i * 16 + l15;
#pragma unroll
    for (int n = 0; n < 2; ++n) {
      uint2 u;
      u.x = cvt2bf(oacc[i][n][0] * inv, oacc[i][n][1] * inv);
      u.y = cvt2bf(oacc[i][n][2] * inv, oacc[i][n][3] * inv);
      *(s16x4*)(ob + (size_t)tok * 384 + h * 32 + n * 16 + g * 4) =
          __builtin_bit_cast(s16x4, u);
    }
  }
}

// ---------------- launch ----------------
extern "C" void kernel_launch(void* const* d_in, const int* in_sizes, int n_in,
                              void* d_out, int out_size, void* d_ws, size_t ws_size,
                              hipStream_t stream) {
  const float* x        = (const float*)d_in[0];   // [4,4096,768]
  const float* W_reduce = (const float*)d_in[1];   // [768,384]
  const float* b_reduce = (const float*)d_in[2];   // [384]
  const float* W_qkv    = (const float*)d_in[3];   // [384,1152]
  const float* b_qkv    = (const float*)d_in[4];   // [1152]
  const float* W_proj   = (const float*)d_in[5];   // [384,768]
  const float* b_proj   = (const float*)d_in[6];   // [768]
  float* out = (float*)d_out;                      // [16384,768]

  char* ws = (char*)d_ws;
  short* wr_t    = (short*)(ws + 0);               // [384][768]    589824 B
  short* wqkv_t  = (short*)(ws + 589824);          // [1152][384]   884736 B
  short* wproj_t = (short*)(ws + 1474560);         // [768][384]    589824 B
  short* xr_b    = (short*)(ws + 2064384);         // [16384][384]  12582912 B
  short* o_b     = xr_b;                           // reuse after qkv GEMM
  short* q_p     = (short*)(ws + 14647296);        // [192][1024][32] 12582912 B
  short* k_p     = (short*)(ws + 27230208);        // 12582912 B
  short* vt      = (short*)(ws + 39813120);        // [192][32][1024] 12582912 B

  // all three weight transposes in one dispatch
  transpose_cast_all<<<1008, 256, 0, stream>>>(W_reduce, wr_t, W_qkv, wqkv_t, W_proj, wproj_t);

  // xr = x @ W_reduce + b_reduce  (f32 A fused-cast, bf16 out) — BM=64: 768 blocks
  gemm_bf16<0, true, 64><<<768, 256, 0, stream>>>(nullptr, x, wr_t, b_reduce, xr_b,
                                                  nullptr, nullptr, nullptr, 16384, 384, 768);
  // qkv = xr @ W_qkv + b_qkv  -> scatter q_p / k_p / vt-direct — BM=64: 2304 blocks
  gemm_bf16<2, false, 64><<<2304, 256, 0, stream>>>(xr_b, nullptr, wqkv_t, b_qkv, nullptr,
                                                    q_p, k_p, vt, 16384, 1152, 384);
  // attention -> o_b  (2-wave blocks, 16 q-tiles per bhs)
  attn_kernel<<<3072, 128, 0, stream>>>(q_p, k_p, vt, o_b);
  // out = o @ W_proj + b_proj (f32 out) — BM=64: 1536 blocks
  gemm_bf16<1, false, 64><<<1536, 256, 0, stream>>>(o_b, nullptr, wproj_t, b_proj, (void*)out,
                                                    nullptr, nullptr, nullptr, 16384, 768, 384);
}